// Round 24
// baseline (147.095 us; speedup 1.0000x reference)
//
#include <hip/hip_runtime.h>
#include <cstddef>

#define BB 4
#define SS 2048
#define DMOD 32
#define AEL (BB*SS*DMOD)            // 262144 floats = 1MB
// ws float-offsets:
#define QBF0 16                     // Qbf bf16 [bp=8][2048][32] (kB)
#define KBF0 (QBF0 + AEL)           // Kbf
#define VF0  (KBF0 + AEL)           // VF bf16 [bp][512][32][4]
#define QSP0 (VF0 + AEL)            // q split bf16 [8192][3][32] (cc-scaled)
#define SPLEN 393216
#define KSP0 (QSP0 + SPLEN)
#define MB0  (KSP0 + SPLEN)         // pmask u64 x MWORDS, then nmask
#define MWORDS (BB*32*SS)           // 262144 u64 per mask
#define DMB0 (MB0 + 4*MWORDS)       // dmask bit words u64 x MWORDS
#define PART0 (DMB0 + 2*MWORDS)
#define PSLOT (36*8192)
#define TINY 1e-30f

typedef __attribute__((ext_vector_type(16))) float f32x16;
typedef __attribute__((ext_vector_type(4)))  short bf16x4;
typedef unsigned short ushortt;
typedef unsigned long long u64;

#if defined(__has_builtin)
#if __has_builtin(__builtin_amdgcn_mfma_f32_32x32x8bf16_1k)
#define HAVE_MFMA328 1
#endif
#if __has_builtin(__builtin_amdgcn_perm)
#define HAVE_PERM 1
#endif
#endif

__device__ __forceinline__ f32x16 mfma328(bf16x4 a, bf16x4 b, f32x16 c) {
#ifdef HAVE_MFMA328
    return __builtin_amdgcn_mfma_f32_32x32x8bf16_1k(a, b, c, 0, 0, 0);
#else
    f32x16 d;
    asm volatile("v_mfma_f32_32x32x8_bf16 %0, %1, %2, %3\n\t"
                 "s_nop 7\n\t"
                 "s_nop 7\n\t"
                 "s_nop 3"
                 : "=&v"(d) : "v"(a), "v"(b), "v"(c));
    return d;
#endif
}

__device__ __forceinline__ float fexp2(float x) {
#if defined(__has_builtin)
#if __has_builtin(__builtin_amdgcn_exp2f)
    return __builtin_amdgcn_exp2f(x);
#else
    return exp2f(x);
#endif
#else
    return exp2f(x);
#endif
}

__device__ __forceinline__ ushortt b1(float a) {
    unsigned u = __float_as_uint(a);
    u += 0x7fffu + ((u >> 16) & 1u);
    return (ushortt)(u >> 16);
}
__device__ __forceinline__ float tof(ushortt h) {
    return __uint_as_float(((unsigned)h) << 16);
}
__device__ __forceinline__ unsigned bfpair(float a, float b) {
    unsigned ua = __float_as_uint(a), ub = __float_as_uint(b);
    ua += 0x7fffu + ((ua >> 16) & 1u);
    ub += 0x7fffu + ((ub >> 16) & 1u);
    return (ua >> 16) | (ub & 0xffff0000u);
}
// truncation-pack of two positive f32 -> {bf16(a) lo, bf16(b) hi} in 1 v_perm_b32
__device__ __forceinline__ unsigned bfpairT(float a, float b) {
#ifdef HAVE_PERM
    return __builtin_amdgcn_perm(__float_as_uint(b), __float_as_uint(a),
                                 0x07060302u);
#else
    return (__float_as_uint(a) >> 16) | (__float_as_uint(b) & 0xffff0000u);
#endif
}
__device__ __forceinline__ bf16x4 packT(float p0, float p1, float p2, float p3) {
    union { unsigned u[2]; bf16x4 v; } c;
    c.u[0] = bfpairT(p0, p1);
    c.u[1] = bfpairT(p2, p3);
    return c.v;
}

// ---------- kernel 1D: fused projections (blocks 0..255) + dmask bits (256..2303) ----------
__global__ __launch_bounds__(256) void k1D_fused(
    const float* __restrict__ feat, const float* __restrict__ dmask,
    const float* __restrict__ qw, const float* __restrict__ qb,
    const float* __restrict__ kw, const float* __restrict__ kb,
    const float* __restrict__ paw, const float* __restrict__ pab,
    const float* __restrict__ naw, const float* __restrict__ nab,
    const float* __restrict__ f1w, const float* __restrict__ f2w,
    const float* __restrict__ f3w,
    float* __restrict__ wsf, u64* __restrict__ dmb) {
    __shared__ float fls[64 * 33];
    int tid = threadIdx.x;
    int blk = blockIdx.x;

    if (blk >= 256) {
        // ---- kD role: dmask -> bit words, transposed layout ----
        int idx = blk - 256;
        int j64 = idx & 31, ib = (idx >> 5) & 15, b = idx >> 9;
        int w = tid >> 6, l = tid & 63;
        const float* src = dmask + (size_t)b*SS*SS + j64*64 + l;
        u64* dst = dmb + (size_t)(b*32 + j64)*SS;
        int i0 = ib*128 + w*32;
        #pragma unroll 8
        for (int r = 0; r < 32; r++) {
            int i = i0 + r;
            float dm = src[(size_t)i*SS];
            u64 bm = __ballot(dm != 0.0f);
            if (l == 0) dst[i] = bm;
        }
        return;
    }

    // ---- k1 role: projections, wave-uniform mat ----
    int w = tid >> 6, lane = tid & 63;
    int rt = blk & 127;
    int mat = (blk >> 7) * 4 + w;

    {
        int fl = tid * 8;
        int rl = fl >> 5, dd = fl & 31;
        const float* src = feat + ((size_t)(rt * 64 + rl)) * DMOD + dd;
        float4 a = *(const float4*)(src);
        float4 b4 = *(const float4*)(src + 4);
        float* dst = fls + rl * 33 + dd;
        dst[0] = a.x; dst[1] = a.y; dst[2] = a.z; dst[3] = a.w;
        dst[4] = b4.x; dst[5] = b4.y; dst[6] = b4.z; dst[7] = b4.w;
    }
    __syncthreads();

    const float* W; const float* Bv; float sc = 1.f;
    switch (mat) {
        case 0: W = qw;        Bv = qb;       break;
        case 1: W = kw;        Bv = kb;       break;
        case 2: W = paw;       Bv = pab;      sc = 0.5101370246954918f; break;
        case 3: W = paw+1024;  Bv = pab+32;   break;
        case 4: W = paw+2048;  Bv = pab+64;   break;
        case 5: W = naw;       Bv = nab;      sc = 0.5101370246954918f; break;
        case 6: W = naw+1024;  Bv = nab+32;   break;
        default:W = naw+2048;  Bv = nab+64;   break;
    }

    int row = rt * 64 + lane;
    const float* fr = fls + lane * 33;
    float acc[32];
    #pragma unroll
    for (int o4 = 0; o4 < 32; o4 += 4) {
        float a0 = Bv[o4], a1 = Bv[o4+1], a2 = Bv[o4+2], a3 = Bv[o4+3];
        #pragma unroll
        for (int d = 0; d < DMOD; d++) {
            float fv = fr[d];
            a0 += fv * W[(o4+0)*DMOD + d];
            a1 += fv * W[(o4+1)*DMOD + d];
            a2 += fv * W[(o4+2)*DMOD + d];
            a3 += fv * W[(o4+3)*DMOD + d];
        }
        acc[o4] = a0; acc[o4+1] = a1; acc[o4+2] = a2; acc[o4+3] = a3;
    }

    if (mat < 2) {
        if (mat == 0) {
            float cc[4];
            #pragma unroll
            for (int h = 0; h < 4; h++) {
                float s = 0.f;
                #pragma unroll
                for (int a = 0; a < 4; a++) {
                    float t = 0.f;
                    #pragma unroll
                    for (int bb = 0; bb < 8; bb++) t += f2w[a*8+bb] * f1w[bb*4+h];
                    s += f3w[a] * t;
                }
                cc[h] = s * 0.35355339059327373f;
            }
            #pragma unroll
            for (int o = 0; o < 32; o++) acc[o] *= cc[o >> 3];
        }
        ushortt* base = (ushortt*)(wsf + (mat == 0 ? QSP0 : KSP0))
                        + (size_t)row * 96;
        ushortt hh[32], mm[32], ll[32];
        #pragma unroll
        for (int o = 0; o < 32; o++) {
            float v = acc[o];
            hh[o] = b1(v);
            float r1 = v - tof(hh[o]);
            mm[o] = b1(r1);
            float r2 = r1 - tof(mm[o]);
            ll[o] = b1(r2);
        }
        #pragma unroll
        for (int o = 0; o < 32; o += 4) {
            *(ushort4*)(base + o)      = make_ushort4(hh[o], hh[o+1], hh[o+2], hh[o+3]);
            *(ushort4*)(base + 32 + o) = make_ushort4(mm[o], mm[o+1], mm[o+2], mm[o+3]);
            *(ushort4*)(base + 64 + o) = make_ushort4(ll[o], ll[o+1], ll[o+2], ll[o+3]);
        }
        return;
    }

    #pragma unroll
    for (int o = 0; o < 32; o++) acc[o] *= sc;
    int b = row >> 11, r2i = row & 2047;
    int pn = (mat >= 5);
    int bp = (b << 1) | pn;
    int m3 = mat - (pn ? 5 : 2);
    if (m3 < 2) {
        unsigned pk[16];
        #pragma unroll
        for (int i = 0; i < 16; i++) pk[i] = bfpair(acc[2*i], acc[2*i+1]);
        unsigned* dst = (unsigned*)((ushortt*)(wsf + (m3 == 0 ? QBF0 : KBF0))
                         + (size_t)bp*65536 + (size_t)r2i*32);
        #pragma unroll
        for (int i = 0; i < 4; i++)
            *(uint4*)(dst + 4*i) = make_uint4(pk[4*i], pk[4*i+1], pk[4*i+2], pk[4*i+3]);
    } else {
        ushortt* vf = (ushortt*)(wsf + VF0)
                         + (size_t)bp*65536 + (size_t)(r2i>>2)*128 + (r2i&3);
        #pragma unroll
        for (int o = 0; o < 32; o++)
            vf[(size_t)o*4] = b1(acc[o]);
    }
}

// ---------- kernel A: MFMA fused-score sign -> packed p/n masks (unchanged) ----------
__global__ __launch_bounds__(256) void kA_mask(
    const u64* __restrict__ dmb,
    const ushortt* __restrict__ qsp, const ushortt* __restrict__ ksp,
    u64* __restrict__ pmout,
    const float* __restrict__ f1b, const float* __restrict__ f2w,
    const float* __restrict__ f2b, const float* __restrict__ f3w,
    const float* __restrict__ f3b) {
    int tid = threadIdx.x;
    int w = tid >> 6, l = tid & 63, li = l & 31, hi = l >> 5;
    int b = blockIdx.z;
    int it = blockIdx.y * 32;
    int j0 = blockIdx.x * 512 + w * 128;

    float cbv = f3b[0];
    #pragma unroll
    for (int a = 0; a < 4; a++) {
        float t = f2b[a];
        #pragma unroll
        for (int bb = 0; bb < 8; bb++) t += f2w[a*8+bb] * f1b[bb];
        cbv += f3w[a] * t;
    }

    const ushortt* qr = qsp + (size_t)(b*SS + it + li)*96 + 4*hi;
    bf16x4 qa[3][4];
    #pragma unroll
    for (int t = 0; t < 3; t++)
        #pragma unroll
        for (int ks = 0; ks < 4; ks++)
            qa[t][ks] = *(const bf16x4*)(qr + t*32 + ks*8);

    const ushortt* kr0 = ksp + (size_t)b*SS*96 + (size_t)li*96 + 4*hi;
    const u64* dmb_b = dmb + (size_t)b*32*SS;
    u64* pm = pmout + (size_t)b*32*SS;
    u64* nm = pmout + MWORDS + (size_t)b*32*SS;

    f32x16 cin;
    #pragma unroll
    for (int r = 0; r < 16; r++) cin[r] = cbv;

    for (int jp = 0; jp < 128; jp += 64) {
        int j64 = (j0 + jp) >> 6;
        u64 dmw[16];
        #pragma unroll
        for (int r = 0; r < 16; r++) {
            int i = it + (r & 3) + 8*(r >> 2) + 4*hi;
            dmw[r] = dmb_b[(size_t)j64*SS + i];
        }
        f32x16 St[2];
        #pragma unroll
        for (int t2 = 0; t2 < 2; t2++) {
            int jt = j0 + jp + t2*32;
            const ushortt* kr = kr0 + (size_t)jt*96;
            bf16x4 kb[3][4];
            #pragma unroll
            for (int t = 0; t < 3; t++)
                #pragma unroll
                for (int ks = 0; ks < 4; ks++)
                    kb[t][ks] = *(const bf16x4*)(kr + t*32 + ks*8);
            f32x16 S = cin;
            #pragma unroll
            for (int ks = 0; ks < 4; ks++) S = mfma328(qa[0][ks], kb[0][ks], S);
            #pragma unroll
            for (int ks = 0; ks < 4; ks++) S = mfma328(qa[0][ks], kb[1][ks], S);
            #pragma unroll
            for (int ks = 0; ks < 4; ks++) S = mfma328(qa[1][ks], kb[0][ks], S);
            #pragma unroll
            for (int ks = 0; ks < 4; ks++) S = mfma328(qa[0][ks], kb[2][ks], S);
            #pragma unroll
            for (int ks = 0; ks < 4; ks++) S = mfma328(qa[2][ks], kb[0][ks], S);
            #pragma unroll
            for (int ks = 0; ks < 4; ks++) S = mfma328(qa[1][ks], kb[1][ks], S);
            St[t2] = S;
        }
        #pragma unroll
        for (int r = 0; r < 16; r++) {
            u64 bs0 = __ballot(St[0][r] > 0.f);
            u64 bs1 = __ballot(St[1][r] > 0.f);
            u64 sA = (bs0 & 0xffffffffull) | (bs1 << 32);
            u64 sB = (bs0 >> 32) | (bs1 & 0xffffffff00000000ull);
            int iA = it + (r & 3) + 8*(r >> 2);
            if (l == 0) {
                u64 dw = dmw[r];
                pm[(size_t)j64*SS + iA] = sA & dw;
                nm[(size_t)j64*SS + iA] = ~sA & dw;
            }
            if (l == 32) {
                u64 dw = dmw[r];
                pm[(size_t)j64*SS + iA + 4] = sB & dw;
                nm[(size_t)j64*SS + iA + 4] = ~sB & dw;
            }
        }
    }
}

// ---------- kernel B: MFMA masked attention — head-split (r22, no setprio) ----------
// grid (nch, 16, 16): z = (b<<2)|(pn<<1)|hp; block 256 = 4 waves, wave = 32-row tile
__global__ __launch_bounds__(256) void kB_attn(
    const ushortt* __restrict__ qbf,
    const ushortt* __restrict__ kbf,
    const ushortt* __restrict__ vff,
    const u64* __restrict__ mall,
    float* __restrict__ part, int CJ, int NCH) {
    int tid = threadIdx.x;
    int w = tid >> 6, l = tid & 63, li = l & 31, hi = l >> 5;
    int jc = blockIdx.x, rg = blockIdx.y, z = blockIdx.z;
    int b = z >> 2, pn = (z >> 1) & 1, hp = z & 1;
    int bp = (b << 1) | pn;
    int h0 = hp * 2;
    int it32 = rg * 128 + w * 32;

    const ushortt* qrow = qbf + (size_t)bp*65536 + (size_t)(it32 + li)*32 + 4*hi;
    bf16x4 qf[2];
    #pragma unroll
    for (int hh = 0; hh < 2; hh++) qf[hh] = *(const bf16x4*)(qrow + (h0+hh)*8);

    const ushortt* kbase = kbf + (size_t)bp*65536 + (size_t)li*32 + 4*hi;
    const ushortt* vbase = vff + (size_t)bp*65536 + (size_t)hi*128;
    const u64* msk = mall + (size_t)pn*MWORDS + (size_t)b*32*SS + (it32 + li);

    bool isl8 = (li == 8);
    bf16x4 ones4;
    {
        union { ushortt s[4]; bf16x4 v; } o;
        o.s[0] = o.s[1] = o.s[2] = o.s[3] = 0x3F80;   // bf16 1.0
        ones4 = o.v;
    }

    f32x16 zero16;
    #pragma unroll
    for (int r = 0; r < 16; r++) zero16[r] = 0.f;
    f32x16 oacc[2];
    #pragma unroll
    for (int hh = 0; hh < 2; hh++)
        #pragma unroll
        for (int r = 0; r < 16; r++) oacc[hh][r] = 0.f;

    int j0 = jc * CJ;
    for (int jw = 0; jw < CJ; jw += 64) {
        u64 mw = msk[(size_t)((j0 + jw) >> 6) * SS];
        #pragma unroll
        for (int half = 0; half < 2; half++) {
            int jt = j0 + jw + half*32;
            unsigned m32 = (unsigned)(mw >> (half*32));
            const ushortt* krow = kbase + (size_t)jt*32;
            const ushortt* vrow = vbase + (size_t)(jt>>2)*128;
            #pragma unroll
            for (int hh = 0; hh < 2; hh++) {
                int h = h0 + hh;
                bf16x4 kf = *(const bf16x4*)(krow + h*8);
                int vcol = ((h*8 + li) & 31) * 4;
                bf16x4 vf0 = *(const bf16x4*)(vrow + 0*256 + vcol);
                bf16x4 vf1 = *(const bf16x4*)(vrow + 1*256 + vcol);
                bf16x4 vf2 = *(const bf16x4*)(vrow + 2*256 + vcol);
                bf16x4 vf3 = *(const bf16x4*)(vrow + 3*256 + vcol);
                if (isl8) { vf0 = ones4; vf1 = ones4; vf2 = ones4; vf3 = ones4; }
                f32x16 sacc = mfma328(kf, qf[hh], zero16);
                float p[16];
                #pragma unroll
                for (int r = 0; r < 16; r++) {
                    int sh = (r & 3) + 8*(r >> 2) + 4*hi;
                    float e = fexp2(sacc[r]);
                    p[r] = ((m32 >> sh) & 1u) ? e : TINY;
                }
                oacc[hh] = mfma328(packT(p[0],  p[1],  p[2],  p[3]),  vf0, oacc[hh]);
                oacc[hh] = mfma328(packT(p[4],  p[5],  p[6],  p[7]),  vf1, oacc[hh]);
                oacc[hh] = mfma328(packT(p[8],  p[9],  p[10], p[11]), vf2, oacc[hh]);
                oacc[hh] = mfma328(packT(p[12], p[13], p[14], p[15]), vf3, oacc[hh]);
            }
        }
    }
    // epilogue: partial slot [pn*NCH+jc][36][8192]; k: 0..3 l[h] (ones column),
    // 4..35 a[h*8+d]
    float* base2 = part + (size_t)(pn * NCH + jc) * PSLOT + (size_t)b * SS;
    if (isl8) {
        #pragma unroll
        for (int hh = 0; hh < 2; hh++) {
            int h = h0 + hh;
            #pragma unroll
            for (int r = 0; r < 16; r++) {
                int irow = it32 + (r & 3) + 8*(r >> 2) + 4*hi;
                base2[(size_t)h * 8192 + irow] = oacc[hh][r];
            }
        }
    }
    if (li < 8) {
        #pragma unroll
        for (int hh = 0; hh < 2; hh++) {
            int h = h0 + hh;
            #pragma unroll
            for (int r = 0; r < 16; r++) {
                int irow = it32 + (r & 3) + 8*(r >> 2) + 4*hi;
                base2[(size_t)(4 + h*8 + li) * 8192 + irow] = oacc[hh][r];
            }
        }
    }
}

// ---------- kernel 3a: reduce split-K partials (r22 version) ----------
__global__ __launch_bounds__(256) void k3a_red(float* __restrict__ part, int NCH) {
    int idx = blockIdx.x * 256 + threadIdx.x;
    size_t e = (size_t)idx * 4;
    int pn = (int)(e / PSLOT);
    size_t off = e - (size_t)pn * PSLOT;
    float* base = part + (size_t)pn * NCH * PSLOT + off;
    float4 s = *(const float4*)base;
    for (int c = 1; c < NCH; c++) {
        float4 v = *(const float4*)(base + (size_t)c * PSLOT);
        s.x += v.x; s.y += v.y; s.z += v.z; s.w += v.w;
    }
    *(float4*)base = s;
}

// ---------- kernel 3b: normalize + out-proj + gate (r22 version) ----------
__global__ __launch_bounds__(256) void k3b_fin(
    const float* __restrict__ part, int NCH,
    const float* __restrict__ paw, const float* __restrict__ pab,
    const float* __restrict__ naw, const float* __restrict__ nab,
    const float* __restrict__ vpw, const float* __restrict__ vpb,
    const float* __restrict__ vnw, const float* __restrict__ vnb,
    const float* __restrict__ gpw, const float* __restrict__ gpb,
    float* __restrict__ out) {
    __shared__ float sums[8][72];
    __shared__ float Pl[8][64];
    __shared__ float pnv[8][64];
    int tid = threadIdx.x;
    int r = tid >> 5, o = tid & 31;
    int row = blockIdx.x * 8 + r;
    const float* b0 = part + row;
    const float* b1 = part + (size_t)NCH * PSLOT + row;
    for (int v = o; v < 72; v += 32) {
        int pn = v >= 36;
        int k = v - 36 * pn;
        sums[r][v] = (pn ? b1 : b0)[(size_t)k * 8192];
    }
    __syncthreads();
    Pl[r][o]      = sums[r][4 + o]  / sums[r][o >> 3];
    Pl[r][32 + o] = sums[r][40 + o] / sums[r][36 + (o >> 3)];
    __syncthreads();
    const float* pw3 = paw + 3*1024; const float* pb3 = pab + 3*32;
    const float* nw3 = naw + 3*1024; const float* nb3 = nab + 3*32;
    float pv = pb3[o], nv = nb3[o];
    #pragma unroll
    for (int d = 0; d < 32; d++) {
        pv += Pl[r][d]      * pw3[o*32 + d];
        nv += Pl[r][32 + d] * nw3[o*32 + d];
    }
    pnv[r][o] = pv; pnv[r][32 + o] = nv;
    __syncthreads();
    float vp = vpb[o], vn = vnb[o], ep = gpb[o], en = gpb[o];
    #pragma unroll
    for (int d = 0; d < 32; d++) {
        float pd = pnv[r][d], nd = pnv[r][32 + d];
        vp += pd * vpw[o*32 + d];
        vn += nd * vnw[o*32 + d];
        ep += pd * gpw[o*32 + d];
        en += nd * gpw[o*32 + d];
    }
    float g = 1.0f / (1.0f + __expf(en - ep));
    out[(size_t)row * 32 + o] = vp * g + vn * (1.0f - g);
}

extern "C" void kernel_launch(void* const* d_in, const int* in_sizes, int n_in,
                              void* d_out, int out_size, void* d_ws, size_t ws_size,
                              hipStream_t stream) {
    const float* feat  = (const float*)d_in[0];
    const float* dmask = (const float*)d_in[1];
    const float* qw  = (const float*)d_in[2];  const float* qb  = (const float*)d_in[3];
    const float* kw  = (const float*)d_in[4];  const float* kb  = (const float*)d_in[5];
    const float* f1w = (const float*)d_in[6];  const float* f1b = (const float*)d_in[7];
    const float* f2w = (const float*)d_in[8];  const float* f2b = (const float*)d_in[9];
    const float* f3w = (const float*)d_in[10]; const float* f3b = (const float*)d_in[11];
    const float* paw = (const float*)d_in[12]; const float* pab = (const float*)d_in[13];
    const float* naw = (const float*)d_in[14]; const float* nab = (const float*)d_in[15];
    const float* vpw = (const float*)d_in[16]; const float* vpb = (const float*)d_in[17];
    const float* vnw = (const float*)d_in[18]; const float* vnb = (const float*)d_in[19];
    const float* gpw = (const float*)d_in[20]; const float* gpb = (const float*)d_in[21];
    float* wsf = (float*)d_ws;
    float* out = (float*)d_out;

    size_t avail = ws_size / 4;
    int nch = 1;
    if (avail > (size_t)PART0) {
        size_t per = (size_t)2 * PSLOT;
        size_t m = (avail - PART0) / per;
        nch = (m >= 8) ? 8 : (m >= 4) ? 4 : (m >= 2) ? 2 : 1;
    }
    int cj = SS / nch;
    float* part = wsf + PART0;

    const ushortt* qbfu = (const ushortt*)(wsf + QBF0);
    const ushortt* kbfu = (const ushortt*)(wsf + KBF0);
    const ushortt* vffu = (const ushortt*)(wsf + VF0);
    const ushortt* qspu = (const ushortt*)(wsf + QSP0);
    const ushortt* kspu = (const ushortt*)(wsf + KSP0);
    u64* dmbu = (u64*)(wsf + DMB0);

    hipLaunchKernelGGL(k1D_fused, dim3(2304), dim3(256), 0, stream,
                       feat, dmask, qw, qb, kw, kb, paw, pab, naw, nab,
                       f1w, f2w, f3w, wsf, dmbu);
    hipLaunchKernelGGL(kA_mask, dim3(4, 64, BB), dim3(256), 0, stream,
                       dmbu, qspu, kspu, (u64*)(wsf + MB0),
                       f1b, f2w, f2b, f3w, f3b);
    hipLaunchKernelGGL(kB_attn, dim3(nch, 16, BB*4), dim3(256), 0, stream,
                       qbfu, kbfu, vffu,
                       (const u64*)(wsf + MB0), part, cj, nch);
    if (nch > 1)
        hipLaunchKernelGGL(k3a_red, dim3(576), dim3(256), 0, stream, part, nch);
    hipLaunchKernelGGL(k3b_fin, dim3(1024), dim3(256), 0, stream,
                       part, nch, paw, pab, naw, nab, vpw, vpb, vnw, vnb, gpw, gpb,
                       out);
}

// Round 25
// 116.252 us; speedup vs baseline: 1.2653x; 1.2653x over previous
//
#include <hip/hip_runtime.h>
#include <cstddef>

#define BB 4
#define SS 2048
#define DMOD 32
#define AEL (BB*SS*DMOD)            // 262144 floats = 1MB
// ws float-offsets:
#define QBF0 16                     // Qbf bf16 [bp=8][2048][32] (kB)
#define KBF0 (QBF0 + AEL)           // Kbf
#define VF0  (KBF0 + AEL)           // VF bf16 [bp][512][32][4]
#define QSP0 (VF0 + AEL)            // q split bf16 [8192][3][32] (cc-scaled)
#define SPLEN 393216
#define KSP0 (QSP0 + SPLEN)
#define MB0  (KSP0 + SPLEN)         // pmask u64 x MWORDS, then nmask
#define MWORDS (BB*32*SS)           // 262144 u64 per mask
#define PART0 (MB0 + 4*MWORDS)
#define PSLOT (36*8192)
#define TINY 1e-30f

typedef __attribute__((ext_vector_type(16))) float f32x16;
typedef __attribute__((ext_vector_type(4)))  short bf16x4;
typedef unsigned short ushortt;
typedef unsigned long long u64;

#if defined(__has_builtin)
#if __has_builtin(__builtin_amdgcn_mfma_f32_32x32x8bf16_1k)
#define HAVE_MFMA328 1
#endif
#if __has_builtin(__builtin_amdgcn_perm)
#define HAVE_PERM 1
#endif
#endif

__device__ __forceinline__ f32x16 mfma328(bf16x4 a, bf16x4 b, f32x16 c) {
#ifdef HAVE_MFMA328
    return __builtin_amdgcn_mfma_f32_32x32x8bf16_1k(a, b, c, 0, 0, 0);
#else
    f32x16 d;
    asm volatile("v_mfma_f32_32x32x8_bf16 %0, %1, %2, %3\n\t"
                 "s_nop 7\n\t"
                 "s_nop 7\n\t"
                 "s_nop 3"
                 : "=&v"(d) : "v"(a), "v"(b), "v"(c));
    return d;
#endif
}

__device__ __forceinline__ float fexp2(float x) {
#if defined(__has_builtin)
#if __has_builtin(__builtin_amdgcn_exp2f)
    return __builtin_amdgcn_exp2f(x);
#else
    return exp2f(x);
#endif
#else
    return exp2f(x);
#endif
}

__device__ __forceinline__ ushortt b1(float a) {
    unsigned u = __float_as_uint(a);
    u += 0x7fffu + ((u >> 16) & 1u);
    return (ushortt)(u >> 16);
}
__device__ __forceinline__ float tof(ushortt h) {
    return __uint_as_float(((unsigned)h) << 16);
}
__device__ __forceinline__ unsigned bfpair(float a, float b) {
    unsigned ua = __float_as_uint(a), ub = __float_as_uint(b);
    ua += 0x7fffu + ((ua >> 16) & 1u);
    ub += 0x7fffu + ((ub >> 16) & 1u);
    return (ua >> 16) | (ub & 0xffff0000u);
}
// truncation-pack of two positive f32 -> {bf16(a) lo, bf16(b) hi} in 1 v_perm_b32
__device__ __forceinline__ unsigned bfpairT(float a, float b) {
#ifdef HAVE_PERM
    return __builtin_amdgcn_perm(__float_as_uint(b), __float_as_uint(a),
                                 0x07060302u);
#else
    return (__float_as_uint(a) >> 16) | (__float_as_uint(b) & 0xffff0000u);
#endif
}
__device__ __forceinline__ bf16x4 packT(float p0, float p1, float p2, float p3) {
    union { unsigned u[2]; bf16x4 v; } c;
    c.u[0] = bfpairT(p0, p1);
    c.u[1] = bfpairT(p2, p3);
    return c.v;
}

// ---------- kernel 1: projections, wave-uniform mat (r22 version) ----------
__global__ __launch_bounds__(256) void k1_proj(
    const float* __restrict__ feat,
    const float* __restrict__ qw, const float* __restrict__ qb,
    const float* __restrict__ kw, const float* __restrict__ kb,
    const float* __restrict__ paw, const float* __restrict__ pab,
    const float* __restrict__ naw, const float* __restrict__ nab,
    const float* __restrict__ f1w, const float* __restrict__ f2w,
    const float* __restrict__ f3w,
    float* __restrict__ wsf) {
    __shared__ float fls[64 * 33];
    int tid = threadIdx.x;
    int w = tid >> 6, lane = tid & 63;
    int rt = blockIdx.x;
    int mat = blockIdx.y * 4 + w;

    {
        int fl = tid * 8;
        int rl = fl >> 5, dd = fl & 31;
        const float* src = feat + ((size_t)(rt * 64 + rl)) * DMOD + dd;
        float4 a = *(const float4*)(src);
        float4 b4 = *(const float4*)(src + 4);
        float* dst = fls + rl * 33 + dd;
        dst[0] = a.x; dst[1] = a.y; dst[2] = a.z; dst[3] = a.w;
        dst[4] = b4.x; dst[5] = b4.y; dst[6] = b4.z; dst[7] = b4.w;
    }
    __syncthreads();

    const float* W; const float* Bv; float sc = 1.f;
    switch (mat) {
        case 0: W = qw;        Bv = qb;       break;
        case 1: W = kw;        Bv = kb;       break;
        case 2: W = paw;       Bv = pab;      sc = 0.5101370246954918f; break;
        case 3: W = paw+1024;  Bv = pab+32;   break;
        case 4: W = paw+2048;  Bv = pab+64;   break;
        case 5: W = naw;       Bv = nab;      sc = 0.5101370246954918f; break;
        case 6: W = naw+1024;  Bv = nab+32;   break;
        default:W = naw+2048;  Bv = nab+64;   break;
    }

    int row = rt * 64 + lane;
    const float* fr = fls + lane * 33;
    float acc[32];
    #pragma unroll
    for (int o4 = 0; o4 < 32; o4 += 4) {
        float a0 = Bv[o4], a1 = Bv[o4+1], a2 = Bv[o4+2], a3 = Bv[o4+3];
        #pragma unroll
        for (int d = 0; d < DMOD; d++) {
            float fv = fr[d];
            a0 += fv * W[(o4+0)*DMOD + d];
            a1 += fv * W[(o4+1)*DMOD + d];
            a2 += fv * W[(o4+2)*DMOD + d];
            a3 += fv * W[(o4+3)*DMOD + d];
        }
        acc[o4] = a0; acc[o4+1] = a1; acc[o4+2] = a2; acc[o4+3] = a3;
    }

    if (mat < 2) {
        if (mat == 0) {
            float cc[4];
            #pragma unroll
            for (int h = 0; h < 4; h++) {
                float s = 0.f;
                #pragma unroll
                for (int a = 0; a < 4; a++) {
                    float t = 0.f;
                    #pragma unroll
                    for (int bb = 0; bb < 8; bb++) t += f2w[a*8+bb] * f1w[bb*4+h];
                    s += f3w[a] * t;
                }
                cc[h] = s * 0.35355339059327373f;
            }
            #pragma unroll
            for (int o = 0; o < 32; o++) acc[o] *= cc[o >> 3];
        }
        ushortt* base = (ushortt*)(wsf + (mat == 0 ? QSP0 : KSP0))
                        + (size_t)row * 96;
        ushortt hh[32], mm[32], ll[32];
        #pragma unroll
        for (int o = 0; o < 32; o++) {
            float v = acc[o];
            hh[o] = b1(v);
            float r1 = v - tof(hh[o]);
            mm[o] = b1(r1);
            float r2 = r1 - tof(mm[o]);
            ll[o] = b1(r2);
        }
        #pragma unroll
        for (int o = 0; o < 32; o += 4) {
            *(ushort4*)(base + o)      = make_ushort4(hh[o], hh[o+1], hh[o+2], hh[o+3]);
            *(ushort4*)(base + 32 + o) = make_ushort4(mm[o], mm[o+1], mm[o+2], mm[o+3]);
            *(ushort4*)(base + 64 + o) = make_ushort4(ll[o], ll[o+1], ll[o+2], ll[o+3]);
        }
        return;
    }

    #pragma unroll
    for (int o = 0; o < 32; o++) acc[o] *= sc;
    int b = row >> 11, r2i = row & 2047;
    int pn = (mat >= 5);
    int bp = (b << 1) | pn;
    int m3 = mat - (pn ? 5 : 2);
    if (m3 < 2) {
        unsigned pk[16];
        #pragma unroll
        for (int i = 0; i < 16; i++) pk[i] = bfpair(acc[2*i], acc[2*i+1]);
        unsigned* dst = (unsigned*)((ushortt*)(wsf + (m3 == 0 ? QBF0 : KBF0))
                         + (size_t)bp*65536 + (size_t)r2i*32);
        #pragma unroll
        for (int i = 0; i < 4; i++)
            *(uint4*)(dst + 4*i) = make_uint4(pk[4*i], pk[4*i+1], pk[4*i+2], pk[4*i+3]);
    } else {
        ushortt* vf = (ushortt*)(wsf + VF0)
                         + (size_t)bp*65536 + (size_t)(r2i>>2)*128 + (r2i&3);
        #pragma unroll
        for (int o = 0; o < 32; o++)
            vf[(size_t)o*4] = b1(acc[o]);
    }
}

// ---------- kernel A: MFMA fused-score sign + dmask fold -> packed p/n masks ----------
// grid (jq=4, is=64, b=4); wave w: j-range 128. dmask floats prefetched per jp
// before the MFMA chain (lane l covers (i(r,hi), j0+jp+t2*32+li) = its ballot bit).
__global__ __launch_bounds__(256) void kA_mask(
    const float* __restrict__ dmask,
    const ushortt* __restrict__ qsp, const ushortt* __restrict__ ksp,
    u64* __restrict__ pmout,
    const float* __restrict__ f1b, const float* __restrict__ f2w,
    const float* __restrict__ f2b, const float* __restrict__ f3w,
    const float* __restrict__ f3b) {
    int tid = threadIdx.x;
    int w = tid >> 6, l = tid & 63, li = l & 31, hi = l >> 5;
    int b = blockIdx.z;
    int it = blockIdx.y * 32;
    int j0 = blockIdx.x * 512 + w * 128;

    float cbv = f3b[0];
    #pragma unroll
    for (int a = 0; a < 4; a++) {
        float t = f2b[a];
        #pragma unroll
        for (int bb = 0; bb < 8; bb++) t += f2w[a*8+bb] * f1b[bb];
        cbv += f3w[a] * t;
    }

    const ushortt* qr = qsp + (size_t)(b*SS + it + li)*96 + 4*hi;
    bf16x4 qa[3][4];
    #pragma unroll
    for (int t = 0; t < 3; t++)
        #pragma unroll
        for (int ks = 0; ks < 4; ks++)
            qa[t][ks] = *(const bf16x4*)(qr + t*32 + ks*8);

    const ushortt* kr0 = ksp + (size_t)b*SS*96 + (size_t)li*96 + 4*hi;
    const float* dmbase = dmask + (size_t)b*SS*SS;
    u64* pm = pmout + (size_t)b*32*SS;
    u64* nm = pmout + MWORDS + (size_t)b*32*SS;

    f32x16 cin;
    #pragma unroll
    for (int r = 0; r < 16; r++) cin[r] = cbv;

    for (int jp = 0; jp < 128; jp += 64) {
        int j64 = (j0 + jp) >> 6;
        // prefetch dm floats for this 64-j window (issued before MFMA chain)
        float dm0[16], dm1[16];
        #pragma unroll
        for (int r = 0; r < 16; r++) {
            int i = it + (r & 3) + 8*(r >> 2) + 4*hi;
            const float* dr = dmbase + (size_t)i*SS + (j0 + jp) + li;
            dm0[r] = dr[0];
            dm1[r] = dr[32];
        }
        f32x16 St[2];
        #pragma unroll
        for (int t2 = 0; t2 < 2; t2++) {
            int jt = j0 + jp + t2*32;
            const ushortt* kr = kr0 + (size_t)jt*96;
            bf16x4 kb[3][4];
            #pragma unroll
            for (int t = 0; t < 3; t++)
                #pragma unroll
                for (int ks = 0; ks < 4; ks++)
                    kb[t][ks] = *(const bf16x4*)(kr + t*32 + ks*8);
            f32x16 S = cin;
            #pragma unroll
            for (int ks = 0; ks < 4; ks++) S = mfma328(qa[0][ks], kb[0][ks], S);
            #pragma unroll
            for (int ks = 0; ks < 4; ks++) S = mfma328(qa[0][ks], kb[1][ks], S);
            #pragma unroll
            for (int ks = 0; ks < 4; ks++) S = mfma328(qa[1][ks], kb[0][ks], S);
            #pragma unroll
            for (int ks = 0; ks < 4; ks++) S = mfma328(qa[0][ks], kb[2][ks], S);
            #pragma unroll
            for (int ks = 0; ks < 4; ks++) S = mfma328(qa[2][ks], kb[0][ks], S);
            #pragma unroll
            for (int ks = 0; ks < 4; ks++) S = mfma328(qa[1][ks], kb[1][ks], S);
            St[t2] = S;
        }
        #pragma unroll
        for (int r = 0; r < 16; r++) {
            bool a0 = (dm0[r] != 0.f), a1 = (dm1[r] != 0.f);
            bool s0 = St[0][r] > 0.f, s1 = St[1][r] > 0.f;
            u64 b0p = __ballot(s0 && a0);
            u64 b1p = __ballot(s1 && a1);
            u64 b0n = __ballot(!s0 && a0);
            u64 b1n = __ballot(!s1 && a1);
            u64 pA = (b0p & 0xffffffffull) | (b1p << 32);
            u64 pB = (b0p >> 32) | (b1p & 0xffffffff00000000ull);
            u64 nA = (b0n & 0xffffffffull) | (b1n << 32);
            u64 nB = (b0n >> 32) | (b1n & 0xffffffff00000000ull);
            int iA = it + (r & 3) + 8*(r >> 2);
            if (l == 0) {
                pm[(size_t)j64*SS + iA] = pA;
                nm[(size_t)j64*SS + iA] = nA;
            }
            if (l == 32) {
                pm[(size_t)j64*SS + iA + 4] = pB;
                nm[(size_t)j64*SS + iA + 4] = nB;
            }
        }
    }
}

// ---------- kernel B: MFMA masked attention — head-split (r22, no setprio) ----------
// grid (nch, 16, 16): z = (b<<2)|(pn<<1)|hp; block 256 = 4 waves, wave = 32-row tile
__global__ __launch_bounds__(256) void kB_attn(
    const ushortt* __restrict__ qbf,
    const ushortt* __restrict__ kbf,
    const ushortt* __restrict__ vff,
    const u64* __restrict__ mall,
    float* __restrict__ part, int CJ, int NCH) {
    int tid = threadIdx.x;
    int w = tid >> 6, l = tid & 63, li = l & 31, hi = l >> 5;
    int jc = blockIdx.x, rg = blockIdx.y, z = blockIdx.z;
    int b = z >> 2, pn = (z >> 1) & 1, hp = z & 1;
    int bp = (b << 1) | pn;
    int h0 = hp * 2;
    int it32 = rg * 128 + w * 32;

    const ushortt* qrow = qbf + (size_t)bp*65536 + (size_t)(it32 + li)*32 + 4*hi;
    bf16x4 qf[2];
    #pragma unroll
    for (int hh = 0; hh < 2; hh++) qf[hh] = *(const bf16x4*)(qrow + (h0+hh)*8);

    const ushortt* kbase = kbf + (size_t)bp*65536 + (size_t)li*32 + 4*hi;
    const ushortt* vbase = vff + (size_t)bp*65536 + (size_t)hi*128;
    const u64* msk = mall + (size_t)pn*MWORDS + (size_t)b*32*SS + (it32 + li);

    bool isl8 = (li == 8);
    bf16x4 ones4;
    {
        union { ushortt s[4]; bf16x4 v; } o;
        o.s[0] = o.s[1] = o.s[2] = o.s[3] = 0x3F80;   // bf16 1.0
        ones4 = o.v;
    }

    f32x16 zero16;
    #pragma unroll
    for (int r = 0; r < 16; r++) zero16[r] = 0.f;
    f32x16 oacc[2];
    #pragma unroll
    for (int hh = 0; hh < 2; hh++)
        #pragma unroll
        for (int r = 0; r < 16; r++) oacc[hh][r] = 0.f;

    int j0 = jc * CJ;
    for (int jw = 0; jw < CJ; jw += 64) {
        u64 mw = msk[(size_t)((j0 + jw) >> 6) * SS];
        #pragma unroll
        for (int half = 0; half < 2; half++) {
            int jt = j0 + jw + half*32;
            unsigned m32 = (unsigned)(mw >> (half*32));
            const ushortt* krow = kbase + (size_t)jt*32;
            const ushortt* vrow = vbase + (size_t)(jt>>2)*128;
            #pragma unroll
            for (int hh = 0; hh < 2; hh++) {
                int h = h0 + hh;
                bf16x4 kf = *(const bf16x4*)(krow + h*8);
                int vcol = ((h*8 + li) & 31) * 4;
                bf16x4 vf0 = *(const bf16x4*)(vrow + 0*256 + vcol);
                bf16x4 vf1 = *(const bf16x4*)(vrow + 1*256 + vcol);
                bf16x4 vf2 = *(const bf16x4*)(vrow + 2*256 + vcol);
                bf16x4 vf3 = *(const bf16x4*)(vrow + 3*256 + vcol);
                if (isl8) { vf0 = ones4; vf1 = ones4; vf2 = ones4; vf3 = ones4; }
                f32x16 sacc = mfma328(kf, qf[hh], zero16);
                float p[16];
                #pragma unroll
                for (int r = 0; r < 16; r++) {
                    int sh = (r & 3) + 8*(r >> 2) + 4*hi;
                    float e = fexp2(sacc[r]);
                    p[r] = ((m32 >> sh) & 1u) ? e : TINY;
                }
                oacc[hh] = mfma328(packT(p[0],  p[1],  p[2],  p[3]),  vf0, oacc[hh]);
                oacc[hh] = mfma328(packT(p[4],  p[5],  p[6],  p[7]),  vf1, oacc[hh]);
                oacc[hh] = mfma328(packT(p[8],  p[9],  p[10], p[11]), vf2, oacc[hh]);
                oacc[hh] = mfma328(packT(p[12], p[13], p[14], p[15]), vf3, oacc[hh]);
            }
        }
    }
    // epilogue: partial slot [pn*NCH+jc][36][8192]; k: 0..3 l[h] (ones column),
    // 4..35 a[h*8+d]
    float* base2 = part + (size_t)(pn * NCH + jc) * PSLOT + (size_t)b * SS;
    if (isl8) {
        #pragma unroll
        for (int hh = 0; hh < 2; hh++) {
            int h = h0 + hh;
            #pragma unroll
            for (int r = 0; r < 16; r++) {
                int irow = it32 + (r & 3) + 8*(r >> 2) + 4*hi;
                base2[(size_t)h * 8192 + irow] = oacc[hh][r];
            }
        }
    }
    if (li < 8) {
        #pragma unroll
        for (int hh = 0; hh < 2; hh++) {
            int h = h0 + hh;
            #pragma unroll
            for (int r = 0; r < 16; r++) {
                int irow = it32 + (r & 3) + 8*(r >> 2) + 4*hi;
                base2[(size_t)(4 + h*8 + li) * 8192 + irow] = oacc[hh][r];
            }
        }
    }
}

// ---------- kernel 3a: reduce split-K partials (r22 version) ----------
__global__ __launch_bounds__(256) void k3a_red(float* __restrict__ part, int NCH) {
    int idx = blockIdx.x * 256 + threadIdx.x;
    size_t e = (size_t)idx * 4;
    int pn = (int)(e / PSLOT);
    size_t off = e - (size_t)pn * PSLOT;
    float* base = part + (size_t)pn * NCH * PSLOT + off;
    float4 s = *(const float4*)base;
    for (int c = 1; c < NCH; c++) {
        float4 v = *(const float4*)(base + (size_t)c * PSLOT);
        s.x += v.x; s.y += v.y; s.z += v.z; s.w += v.w;
    }
    *(float4*)base = s;
}

// ---------- kernel 3b: normalize + out-proj + gate (r22 version) ----------
__global__ __launch_bounds__(256) void k3b_fin(
    const float* __restrict__ part, int NCH,
    const float* __restrict__ paw, const float* __restrict__ pab,
    const float* __restrict__ naw, const float* __restrict__ nab,
    const float* __restrict__ vpw, const float* __restrict__ vpb,
    const float* __restrict__ vnw, const float* __restrict__ vnb,
    const float* __restrict__ gpw, const float* __restrict__ gpb,
    float* __restrict__ out) {
    __shared__ float sums[8][72];
    __shared__ float Pl[8][64];
    __shared__ float pnv[8][64];
    int tid = threadIdx.x;
    int r = tid >> 5, o = tid & 31;
    int row = blockIdx.x * 8 + r;
    const float* b0 = part + row;
    const float* b1 = part + (size_t)NCH * PSLOT + row;
    for (int v = o; v < 72; v += 32) {
        int pn = v >= 36;
        int k = v - 36 * pn;
        sums[r][v] = (pn ? b1 : b0)[(size_t)k * 8192];
    }
    __syncthreads();
    Pl[r][o]      = sums[r][4 + o]  / sums[r][o >> 3];
    Pl[r][32 + o] = sums[r][40 + o] / sums[r][36 + (o >> 3)];
    __syncthreads();
    const float* pw3 = paw + 3*1024; const float* pb3 = pab + 3*32;
    const float* nw3 = naw + 3*1024; const float* nb3 = nab + 3*32;
    float pv = pb3[o], nv = nb3[o];
    #pragma unroll
    for (int d = 0; d < 32; d++) {
        pv += Pl[r][d]      * pw3[o*32 + d];
        nv += Pl[r][32 + d] * nw3[o*32 + d];
    }
    pnv[r][o] = pv; pnv[r][32 + o] = nv;
    __syncthreads();
    float vp = vpb[o], vn = vnb[o], ep = gpb[o], en = gpb[o];
    #pragma unroll
    for (int d = 0; d < 32; d++) {
        float pd = pnv[r][d], nd = pnv[r][32 + d];
        vp += pd * vpw[o*32 + d];
        vn += nd * vnw[o*32 + d];
        ep += pd * gpw[o*32 + d];
        en += nd * gpw[o*32 + d];
    }
    float g = 1.0f / (1.0f + __expf(en - ep));
    out[(size_t)row * 32 + o] = vp * g + vn * (1.0f - g);
}

extern "C" void kernel_launch(void* const* d_in, const int* in_sizes, int n_in,
                              void* d_out, int out_size, void* d_ws, size_t ws_size,
                              hipStream_t stream) {
    const float* feat  = (const float*)d_in[0];
    const float* dmask = (const float*)d_in[1];
    const float* qw  = (const float*)d_in[2];  const float* qb  = (const float*)d_in[3];
    const float* kw  = (const float*)d_in[4];  const float* kb  = (const float*)d_in[5];
    const float* f1w = (const float*)d_in[6];  const float* f1b = (const float*)d_in[7];
    const float* f2w = (const float*)d_in[8];  const float* f2b = (const float*)d_in[9];
    const float* f3w = (const float*)d_in[10]; const float* f3b = (const float*)d_in[11];
    const float* paw = (const float*)d_in[12]; const float* pab = (const float*)d_in[13];
    const float* naw = (const float*)d_in[14]; const float* nab = (const float*)d_in[15];
    const float* vpw = (const float*)d_in[16]; const float* vpb = (const float*)d_in[17];
    const float* vnw = (const float*)d_in[18]; const float* vnb = (const float*)d_in[19];
    const float* gpw = (const float*)d_in[20]; const float* gpb = (const float*)d_in[21];
    float* wsf = (float*)d_ws;
    float* out = (float*)d_out;

    size_t avail = ws_size / 4;
    int nch = 1;
    if (avail > (size_t)PART0) {
        size_t per = (size_t)2 * PSLOT;
        size_t m = (avail - PART0) / per;
        nch = (m >= 8) ? 8 : (m >= 4) ? 4 : (m >= 2) ? 2 : 1;
    }
    int cj = SS / nch;
    float* part = wsf + PART0;

    const ushortt* qbfu = (const ushortt*)(wsf + QBF0);
    const ushortt* kbfu = (const ushortt*)(wsf + KBF0);
    const ushortt* vffu = (const ushortt*)(wsf + VF0);
    const ushortt* qspu = (const ushortt*)(wsf + QSP0);
    const ushortt* kspu = (const ushortt*)(wsf + KSP0);

    hipLaunchKernelGGL(k1_proj, dim3(128, 2), dim3(256), 0, stream,
                       feat, qw, qb, kw, kb, paw, pab, naw, nab,
                       f1w, f2w, f3w, wsf);
    hipLaunchKernelGGL(kA_mask, dim3(4, 64, BB), dim3(256), 0, stream,
                       dmask, qspu, kspu, (u64*)(wsf + MB0),
                       f1b, f2w, f2b, f3w, f3b);
    hipLaunchKernelGGL(kB_attn, dim3(nch, 16, BB*4), dim3(256), 0, stream,
                       qbfu, kbfu, vffu,
                       (const u64*)(wsf + MB0), part, cj, nch);
    if (nch > 1)
        hipLaunchKernelGGL(k3a_red, dim3(576), dim3(256), 0, stream, part, nch);
    hipLaunchKernelGGL(k3b_fin, dim3(1024), dim3(256), 0, stream,
                       part, nch, paw, pab, naw, nab, vpw, vpb, vnw, vnb, gpw, gpb,
                       out);
}

// Round 26
// 112.429 us; speedup vs baseline: 1.3083x; 1.0340x over previous
//
#include <hip/hip_runtime.h>
#include <cstddef>

#define BB 4
#define SS 2048
#define DMOD 32
#define AEL (BB*SS*DMOD)            // 262144 floats = 1MB
// ws float-offsets:
#define QBF0 16                     // Qbf bf16 [bp=8][2048][32] (kB)
#define KBF0 (QBF0 + AEL)           // Kbf
#define VF0  (KBF0 + AEL)           // VF bf16 [bp][512][32][4]
#define QSP0 (VF0 + AEL)            // q split bf16 [8192][3][32] (cc-scaled)
#define SPLEN 393216
#define KSP0 (QSP0 + SPLEN)
#define MB0  (KSP0 + SPLEN)         // pmask u64 x MWORDS, then nmask
#define MWORDS (BB*32*SS)           // 262144 u64 per mask
#define PART0 (MB0 + 4*MWORDS)
#define PSLOT (36*8192)
#define TINY 1e-30f

typedef __attribute__((ext_vector_type(16))) float f32x16;
typedef __attribute__((ext_vector_type(4)))  short bf16x4;
typedef unsigned short ushortt;
typedef unsigned long long u64;

#if defined(__has_builtin)
#if __has_builtin(__builtin_amdgcn_mfma_f32_32x32x8bf16_1k)
#define HAVE_MFMA328 1
#endif
#if __has_builtin(__builtin_amdgcn_perm)
#define HAVE_PERM 1
#endif
#endif

__device__ __forceinline__ f32x16 mfma328(bf16x4 a, bf16x4 b, f32x16 c) {
#ifdef HAVE_MFMA328
    return __builtin_amdgcn_mfma_f32_32x32x8bf16_1k(a, b, c, 0, 0, 0);
#else
    f32x16 d;
    asm volatile("v_mfma_f32_32x32x8_bf16 %0, %1, %2, %3\n\t"
                 "s_nop 7\n\t"
                 "s_nop 7\n\t"
                 "s_nop 3"
                 : "=&v"(d) : "v"(a), "v"(b), "v"(c));
    return d;
#endif
}

__device__ __forceinline__ float fexp2(float x) {
#if defined(__has_builtin)
#if __has_builtin(__builtin_amdgcn_exp2f)
    return __builtin_amdgcn_exp2f(x);
#else
    return exp2f(x);
#endif
#else
    return exp2f(x);
#endif
}

__device__ __forceinline__ ushortt b1(float a) {
    unsigned u = __float_as_uint(a);
    u += 0x7fffu + ((u >> 16) & 1u);
    return (ushortt)(u >> 16);
}
__device__ __forceinline__ float tof(ushortt h) {
    return __uint_as_float(((unsigned)h) << 16);
}
__device__ __forceinline__ unsigned bfpair(float a, float b) {
    unsigned ua = __float_as_uint(a), ub = __float_as_uint(b);
    ua += 0x7fffu + ((ua >> 16) & 1u);
    ub += 0x7fffu + ((ub >> 16) & 1u);
    return (ua >> 16) | (ub & 0xffff0000u);
}
// truncation-pack of two positive f32 -> {bf16(a) lo, bf16(b) hi} in 1 v_perm_b32
__device__ __forceinline__ unsigned bfpairT(float a, float b) {
#ifdef HAVE_PERM
    return __builtin_amdgcn_perm(__float_as_uint(b), __float_as_uint(a),
                                 0x07060302u);
#else
    return (__float_as_uint(a) >> 16) | (__float_as_uint(b) & 0xffff0000u);
#endif
}
__device__ __forceinline__ bf16x4 packT(float p0, float p1, float p2, float p3) {
    union { unsigned u[2]; bf16x4 v; } c;
    c.u[0] = bfpairT(p0, p1);
    c.u[1] = bfpairT(p2, p3);
    return c.v;
}

// ---------- kernel 1: projections, wave-uniform mat (unchanged) ----------
__global__ __launch_bounds__(256) void k1_proj(
    const float* __restrict__ feat,
    const float* __restrict__ qw, const float* __restrict__ qb,
    const float* __restrict__ kw, const float* __restrict__ kb,
    const float* __restrict__ paw, const float* __restrict__ pab,
    const float* __restrict__ naw, const float* __restrict__ nab,
    const float* __restrict__ f1w, const float* __restrict__ f2w,
    const float* __restrict__ f3w,
    float* __restrict__ wsf) {
    __shared__ float fls[64 * 33];
    int tid = threadIdx.x;
    int w = tid >> 6, lane = tid & 63;
    int rt = blockIdx.x;
    int mat = blockIdx.y * 4 + w;

    {
        int fl = tid * 8;
        int rl = fl >> 5, dd = fl & 31;
        const float* src = feat + ((size_t)(rt * 64 + rl)) * DMOD + dd;
        float4 a = *(const float4*)(src);
        float4 b4 = *(const float4*)(src + 4);
        float* dst = fls + rl * 33 + dd;
        dst[0] = a.x; dst[1] = a.y; dst[2] = a.z; dst[3] = a.w;
        dst[4] = b4.x; dst[5] = b4.y; dst[6] = b4.z; dst[7] = b4.w;
    }
    __syncthreads();

    const float* W; const float* Bv; float sc = 1.f;
    switch (mat) {
        case 0: W = qw;        Bv = qb;       break;
        case 1: W = kw;        Bv = kb;       break;
        case 2: W = paw;       Bv = pab;      sc = 0.5101370246954918f; break;
        case 3: W = paw+1024;  Bv = pab+32;   break;
        case 4: W = paw+2048;  Bv = pab+64;   break;
        case 5: W = naw;       Bv = nab;      sc = 0.5101370246954918f; break;
        case 6: W = naw+1024;  Bv = nab+32;   break;
        default:W = naw+2048;  Bv = nab+64;   break;
    }

    int row = rt * 64 + lane;
    const float* fr = fls + lane * 33;
    float acc[32];
    #pragma unroll
    for (int o4 = 0; o4 < 32; o4 += 4) {
        float a0 = Bv[o4], a1 = Bv[o4+1], a2 = Bv[o4+2], a3 = Bv[o4+3];
        #pragma unroll
        for (int d = 0; d < DMOD; d++) {
            float fv = fr[d];
            a0 += fv * W[(o4+0)*DMOD + d];
            a1 += fv * W[(o4+1)*DMOD + d];
            a2 += fv * W[(o4+2)*DMOD + d];
            a3 += fv * W[(o4+3)*DMOD + d];
        }
        acc[o4] = a0; acc[o4+1] = a1; acc[o4+2] = a2; acc[o4+3] = a3;
    }

    if (mat < 2) {
        if (mat == 0) {
            float cc[4];
            #pragma unroll
            for (int h = 0; h < 4; h++) {
                float s = 0.f;
                #pragma unroll
                for (int a = 0; a < 4; a++) {
                    float t = 0.f;
                    #pragma unroll
                    for (int bb = 0; bb < 8; bb++) t += f2w[a*8+bb] * f1w[bb*4+h];
                    s += f3w[a] * t;
                }
                cc[h] = s * 0.35355339059327373f;
            }
            #pragma unroll
            for (int o = 0; o < 32; o++) acc[o] *= cc[o >> 3];
        }
        ushortt* base = (ushortt*)(wsf + (mat == 0 ? QSP0 : KSP0))
                        + (size_t)row * 96;
        ushortt hh[32], mm[32], ll[32];
        #pragma unroll
        for (int o = 0; o < 32; o++) {
            float v = acc[o];
            hh[o] = b1(v);
            float r1 = v - tof(hh[o]);
            mm[o] = b1(r1);
            float r2 = r1 - tof(mm[o]);
            ll[o] = b1(r2);
        }
        #pragma unroll
        for (int o = 0; o < 32; o += 4) {
            *(ushort4*)(base + o)      = make_ushort4(hh[o], hh[o+1], hh[o+2], hh[o+3]);
            *(ushort4*)(base + 32 + o) = make_ushort4(mm[o], mm[o+1], mm[o+2], mm[o+3]);
            *(ushort4*)(base + 64 + o) = make_ushort4(ll[o], ll[o+1], ll[o+2], ll[o+3]);
        }
        return;
    }

    #pragma unroll
    for (int o = 0; o < 32; o++) acc[o] *= sc;
    int b = row >> 11, r2i = row & 2047;
    int pn = (mat >= 5);
    int bp = (b << 1) | pn;
    int m3 = mat - (pn ? 5 : 2);
    if (m3 < 2) {
        unsigned pk[16];
        #pragma unroll
        for (int i = 0; i < 16; i++) pk[i] = bfpair(acc[2*i], acc[2*i+1]);
        unsigned* dst = (unsigned*)((ushortt*)(wsf + (m3 == 0 ? QBF0 : KBF0))
                         + (size_t)bp*65536 + (size_t)r2i*32);
        #pragma unroll
        for (int i = 0; i < 4; i++)
            *(uint4*)(dst + 4*i) = make_uint4(pk[4*i], pk[4*i+1], pk[4*i+2], pk[4*i+3]);
    } else {
        ushortt* vf = (ushortt*)(wsf + VF0)
                         + (size_t)bp*65536 + (size_t)(r2i>>2)*128 + (r2i&3);
        #pragma unroll
        for (int o = 0; o < 32; o++)
            vf[(size_t)o*4] = b1(acc[o]);
    }
}

// ---------- kernel A: MFMA fused-score sign + dmask fold -> packed p/n masks ----------
// grid (jq=8, is=64, b=4) = 2048 blocks; wave w: j-range 64 (one 64-j window).
__global__ __launch_bounds__(256) void kA_mask(
    const float* __restrict__ dmask,
    const ushortt* __restrict__ qsp, const ushortt* __restrict__ ksp,
    u64* __restrict__ pmout,
    const float* __restrict__ f1b, const float* __restrict__ f2w,
    const float* __restrict__ f2b, const float* __restrict__ f3w,
    const float* __restrict__ f3b) {
    int tid = threadIdx.x;
    int w = tid >> 6, l = tid & 63, li = l & 31, hi = l >> 5;
    int b = blockIdx.z;
    int it = blockIdx.y * 32;
    int j0 = blockIdx.x * 256 + w * 64;

    float cbv = f3b[0];
    #pragma unroll
    for (int a = 0; a < 4; a++) {
        float t = f2b[a];
        #pragma unroll
        for (int bb = 0; bb < 8; bb++) t += f2w[a*8+bb] * f1b[bb];
        cbv += f3w[a] * t;
    }

    const ushortt* qr = qsp + (size_t)(b*SS + it + li)*96 + 4*hi;
    bf16x4 qa[3][4];
    #pragma unroll
    for (int t = 0; t < 3; t++)
        #pragma unroll
        for (int ks = 0; ks < 4; ks++)
            qa[t][ks] = *(const bf16x4*)(qr + t*32 + ks*8);

    const ushortt* kr0 = ksp + (size_t)b*SS*96 + (size_t)li*96 + 4*hi;
    const float* dmbase = dmask + (size_t)b*SS*SS;
    u64* pm = pmout + (size_t)b*32*SS;
    u64* nm = pmout + MWORDS + (size_t)b*32*SS;

    f32x16 cin;
    #pragma unroll
    for (int r = 0; r < 16; r++) cin[r] = cbv;

    int j64 = j0 >> 6;
    // prefetch dm floats for this 64-j window (issued before MFMA chain)
    float dm0[16], dm1[16];
    #pragma unroll
    for (int r = 0; r < 16; r++) {
        int i = it + (r & 3) + 8*(r >> 2) + 4*hi;
        const float* dr = dmbase + (size_t)i*SS + j0 + li;
        dm0[r] = dr[0];
        dm1[r] = dr[32];
    }
    f32x16 St[2];
    #pragma unroll
    for (int t2 = 0; t2 < 2; t2++) {
        int jt = j0 + t2*32;
        const ushortt* kr = kr0 + (size_t)jt*96;
        bf16x4 kb[3][4];
        #pragma unroll
        for (int t = 0; t < 3; t++)
            #pragma unroll
            for (int ks = 0; ks < 4; ks++)
                kb[t][ks] = *(const bf16x4*)(kr + t*32 + ks*8);
        f32x16 S = cin;
        #pragma unroll
        for (int ks = 0; ks < 4; ks++) S = mfma328(qa[0][ks], kb[0][ks], S);
        #pragma unroll
        for (int ks = 0; ks < 4; ks++) S = mfma328(qa[0][ks], kb[1][ks], S);
        #pragma unroll
        for (int ks = 0; ks < 4; ks++) S = mfma328(qa[1][ks], kb[0][ks], S);
        #pragma unroll
        for (int ks = 0; ks < 4; ks++) S = mfma328(qa[0][ks], kb[2][ks], S);
        #pragma unroll
        for (int ks = 0; ks < 4; ks++) S = mfma328(qa[2][ks], kb[0][ks], S);
        #pragma unroll
        for (int ks = 0; ks < 4; ks++) S = mfma328(qa[1][ks], kb[1][ks], S);
        St[t2] = S;
    }
    #pragma unroll
    for (int r = 0; r < 16; r++) {
        bool a0 = (dm0[r] != 0.f), a1 = (dm1[r] != 0.f);
        bool s0 = St[0][r] > 0.f, s1 = St[1][r] > 0.f;
        u64 b0p = __ballot(s0 && a0);
        u64 b1p = __ballot(s1 && a1);
        u64 b0n = __ballot(!s0 && a0);
        u64 b1n = __ballot(!s1 && a1);
        u64 pA = (b0p & 0xffffffffull) | (b1p << 32);
        u64 pB = (b0p >> 32) | (b1p & 0xffffffff00000000ull);
        u64 nA = (b0n & 0xffffffffull) | (b1n << 32);
        u64 nB = (b0n >> 32) | (b1n & 0xffffffff00000000ull);
        int iA = it + (r & 3) + 8*(r >> 2);
        if (l == 0) {
            pm[(size_t)j64*SS + iA] = pA;
            nm[(size_t)j64*SS + iA] = nA;
        }
        if (l == 32) {
            pm[(size_t)j64*SS + iA + 4] = pB;
            nm[(size_t)j64*SS + iA + 4] = nB;
        }
    }
}

// ---------- kernel B: MFMA masked attention — head-split (r22, no setprio) ----------
// grid (nch, 16, 16): z = (b<<2)|(pn<<1)|hp; block 256 = 4 waves, wave = 32-row tile
__global__ __launch_bounds__(256) void kB_attn(
    const ushortt* __restrict__ qbf,
    const ushortt* __restrict__ kbf,
    const ushortt* __restrict__ vff,
    const u64* __restrict__ mall,
    float* __restrict__ part, int CJ, int NCH) {
    int tid = threadIdx.x;
    int w = tid >> 6, l = tid & 63, li = l & 31, hi = l >> 5;
    int jc = blockIdx.x, rg = blockIdx.y, z = blockIdx.z;
    int b = z >> 2, pn = (z >> 1) & 1, hp = z & 1;
    int bp = (b << 1) | pn;
    int h0 = hp * 2;
    int it32 = rg * 128 + w * 32;

    const ushortt* qrow = qbf + (size_t)bp*65536 + (size_t)(it32 + li)*32 + 4*hi;
    bf16x4 qf[2];
    #pragma unroll
    for (int hh = 0; hh < 2; hh++) qf[hh] = *(const bf16x4*)(qrow + (h0+hh)*8);

    const ushortt* kbase = kbf + (size_t)bp*65536 + (size_t)li*32 + 4*hi;
    const ushortt* vbase = vff + (size_t)bp*65536 + (size_t)hi*128;
    const u64* msk = mall + (size_t)pn*MWORDS + (size_t)b*32*SS + (it32 + li);

    bool isl8 = (li == 8);
    bf16x4 ones4;
    {
        union { ushortt s[4]; bf16x4 v; } o;
        o.s[0] = o.s[1] = o.s[2] = o.s[3] = 0x3F80;   // bf16 1.0
        ones4 = o.v;
    }

    f32x16 zero16;
    #pragma unroll
    for (int r = 0; r < 16; r++) zero16[r] = 0.f;
    f32x16 oacc[2];
    #pragma unroll
    for (int hh = 0; hh < 2; hh++)
        #pragma unroll
        for (int r = 0; r < 16; r++) oacc[hh][r] = 0.f;

    int j0 = jc * CJ;
    for (int jw = 0; jw < CJ; jw += 64) {
        u64 mw = msk[(size_t)((j0 + jw) >> 6) * SS];
        #pragma unroll
        for (int half = 0; half < 2; half++) {
            int jt = j0 + jw + half*32;
            unsigned m32 = (unsigned)(mw >> (half*32));
            const ushortt* krow = kbase + (size_t)jt*32;
            const ushortt* vrow = vbase + (size_t)(jt>>2)*128;
            #pragma unroll
            for (int hh = 0; hh < 2; hh++) {
                int h = h0 + hh;
                bf16x4 kf = *(const bf16x4*)(krow + h*8);
                int vcol = ((h*8 + li) & 31) * 4;
                bf16x4 vf0 = *(const bf16x4*)(vrow + 0*256 + vcol);
                bf16x4 vf1 = *(const bf16x4*)(vrow + 1*256 + vcol);
                bf16x4 vf2 = *(const bf16x4*)(vrow + 2*256 + vcol);
                bf16x4 vf3 = *(const bf16x4*)(vrow + 3*256 + vcol);
                if (isl8) { vf0 = ones4; vf1 = ones4; vf2 = ones4; vf3 = ones4; }
                f32x16 sacc = mfma328(kf, qf[hh], zero16);
                float p[16];
                #pragma unroll
                for (int r = 0; r < 16; r++) {
                    int sh = (r & 3) + 8*(r >> 2) + 4*hi;
                    float e = fexp2(sacc[r]);
                    p[r] = ((m32 >> sh) & 1u) ? e : TINY;
                }
                oacc[hh] = mfma328(packT(p[0],  p[1],  p[2],  p[3]),  vf0, oacc[hh]);
                oacc[hh] = mfma328(packT(p[4],  p[5],  p[6],  p[7]),  vf1, oacc[hh]);
                oacc[hh] = mfma328(packT(p[8],  p[9],  p[10], p[11]), vf2, oacc[hh]);
                oacc[hh] = mfma328(packT(p[12], p[13], p[14], p[15]), vf3, oacc[hh]);
            }
        }
    }
    // epilogue: partial slot [pn*NCH+jc][36][8192]; k: 0..3 l[h] (ones column),
    // 4..35 a[h*8+d]
    float* base2 = part + (size_t)(pn * NCH + jc) * PSLOT + (size_t)b * SS;
    if (isl8) {
        #pragma unroll
        for (int hh = 0; hh < 2; hh++) {
            int h = h0 + hh;
            #pragma unroll
            for (int r = 0; r < 16; r++) {
                int irow = it32 + (r & 3) + 8*(r >> 2) + 4*hi;
                base2[(size_t)h * 8192 + irow] = oacc[hh][r];
            }
        }
    }
    if (li < 8) {
        #pragma unroll
        for (int hh = 0; hh < 2; hh++) {
            int h = h0 + hh;
            #pragma unroll
            for (int r = 0; r < 16; r++) {
                int irow = it32 + (r & 3) + 8*(r >> 2) + 4*hi;
                base2[(size_t)(4 + h*8 + li) * 8192 + irow] = oacc[hh][r];
            }
        }
    }
}

// ---------- kernel 3a: reduce split-K partials (unchanged) ----------
__global__ __launch_bounds__(256) void k3a_red(float* __restrict__ part, int NCH) {
    int idx = blockIdx.x * 256 + threadIdx.x;
    size_t e = (size_t)idx * 4;
    int pn = (int)(e / PSLOT);
    size_t off = e - (size_t)pn * PSLOT;
    float* base = part + (size_t)pn * NCH * PSLOT + off;
    float4 s = *(const float4*)base;
    for (int c = 1; c < NCH; c++) {
        float4 v = *(const float4*)(base + (size_t)c * PSLOT);
        s.x += v.x; s.y += v.y; s.z += v.z; s.w += v.w;
    }
    *(float4*)base = s;
}

// ---------- kernel 3b: normalize + out-proj + gate (unchanged) ----------
__global__ __launch_bounds__(256) void k3b_fin(
    const float* __restrict__ part, int NCH,
    const float* __restrict__ paw, const float* __restrict__ pab,
    const float* __restrict__ naw, const float* __restrict__ nab,
    const float* __restrict__ vpw, const float* __restrict__ vpb,
    const float* __restrict__ vnw, const float* __restrict__ vnb,
    const float* __restrict__ gpw, const float* __restrict__ gpb,
    float* __restrict__ out) {
    __shared__ float sums[8][72];
    __shared__ float Pl[8][64];
    __shared__ float pnv[8][64];
    int tid = threadIdx.x;
    int r = tid >> 5, o = tid & 31;
    int row = blockIdx.x * 8 + r;
    const float* b0 = part + row;
    const float* b1 = part + (size_t)NCH * PSLOT + row;
    for (int v = o; v < 72; v += 32) {
        int pn = v >= 36;
        int k = v - 36 * pn;
        sums[r][v] = (pn ? b1 : b0)[(size_t)k * 8192];
    }
    __syncthreads();
    Pl[r][o]      = sums[r][4 + o]  / sums[r][o >> 3];
    Pl[r][32 + o] = sums[r][40 + o] / sums[r][36 + (o >> 3)];
    __syncthreads();
    const float* pw3 = paw + 3*1024; const float* pb3 = pab + 3*32;
    const float* nw3 = naw + 3*1024; const float* nb3 = nab + 3*32;
    float pv = pb3[o], nv = nb3[o];
    #pragma unroll
    for (int d = 0; d < 32; d++) {
        pv += Pl[r][d]      * pw3[o*32 + d];
        nv += Pl[r][32 + d] * nw3[o*32 + d];
    }
    pnv[r][o] = pv; pnv[r][32 + o] = nv;
    __syncthreads();
    float vp = vpb[o], vn = vnb[o], ep = gpb[o], en = gpb[o];
    #pragma unroll
    for (int d = 0; d < 32; d++) {
        float pd = pnv[r][d], nd = pnv[r][32 + d];
        vp += pd * vpw[o*32 + d];
        vn += nd * vnw[o*32 + d];
        ep += pd * gpw[o*32 + d];
        en += nd * gpw[o*32 + d];
    }
    float g = 1.0f / (1.0f + __expf(en - ep));
    out[(size_t)row * 32 + o] = vp * g + vn * (1.0f - g);
}

extern "C" void kernel_launch(void* const* d_in, const int* in_sizes, int n_in,
                              void* d_out, int out_size, void* d_ws, size_t ws_size,
                              hipStream_t stream) {
    const float* feat  = (const float*)d_in[0];
    const float* dmask = (const float*)d_in[1];
    const float* qw  = (const float*)d_in[2];  const float* qb  = (const float*)d_in[3];
    const float* kw  = (const float*)d_in[4];  const float* kb  = (const float*)d_in[5];
    const float* f1w = (const float*)d_in[6];  const float* f1b = (const float*)d_in[7];
    const float* f2w = (const float*)d_in[8];  const float* f2b = (const float*)d_in[9];
    const float* f3w = (const float*)d_in[10]; const float* f3b = (const float*)d_in[11];
    const float* paw = (const float*)d_in[12]; const float* pab = (const float*)d_in[13];
    const float* naw = (const float*)d_in[14]; const float* nab = (const float*)d_in[15];
    const float* vpw = (const float*)d_in[16]; const float* vpb = (const float*)d_in[17];
    const float* vnw = (const float*)d_in[18]; const float* vnb = (const float*)d_in[19];
    const float* gpw = (const float*)d_in[20]; const float* gpb = (const float*)d_in[21];
    float* wsf = (float*)d_ws;
    float* out = (float*)d_out;

    size_t avail = ws_size / 4;
    int nch = 1;
    if (avail > (size_t)PART0) {
        size_t per = (size_t)2 * PSLOT;
        size_t m = (avail - PART0) / per;
        nch = (m >= 8) ? 8 : (m >= 4) ? 4 : (m >= 2) ? 2 : 1;
    }
    int cj = SS / nch;
    float* part = wsf + PART0;

    const ushortt* qbfu = (const ushortt*)(wsf + QBF0);
    const ushortt* kbfu = (const ushortt*)(wsf + KBF0);
    const ushortt* vffu = (const ushortt*)(wsf + VF0);
    const ushortt* qspu = (const ushortt*)(wsf + QSP0);
    const ushortt* kspu = (const ushortt*)(wsf + KSP0);

    hipLaunchKernelGGL(k1_proj, dim3(128, 2), dim3(256), 0, stream,
                       feat, qw, qb, kw, kb, paw, pab, naw, nab,
                       f1w, f2w, f3w, wsf);
    hipLaunchKernelGGL(kA_mask, dim3(8, 64, BB), dim3(256), 0, stream,
                       dmask, qspu, kspu, (u64*)(wsf + MB0),
                       f1b, f2w, f2b, f3w, f3b);
    hipLaunchKernelGGL(kB_attn, dim3(nch, 16, BB*4), dim3(256), 0, stream,
                       qbfu, kbfu, vffu,
                       (const u64*)(wsf + MB0), part, cj, nch);
    if (nch > 1)
        hipLaunchKernelGGL(k3a_red, dim3(576), dim3(256), 0, stream, part, nch);
    hipLaunchKernelGGL(k3b_fin, dim3(1024), dim3(256), 0, stream,
                       part, nch, paw, pab, naw, nab, vpw, vpb, vnw, vnb, gpw, gpb,
                       out);
}

// Round 27
// 105.465 us; speedup vs baseline: 1.3947x; 1.0660x over previous
//
#include <hip/hip_runtime.h>
#include <cstddef>

#define BB 4
#define SS 2048
#define DMOD 32
#define AEL (BB*SS*DMOD)            // 262144 floats = 1MB
// ws float-offsets:
#define QBF0 16                     // Qbf bf16 [bp=8][2048][32] (kB)
#define KBF0 (QBF0 + AEL)           // Kbf
#define VF0  (KBF0 + AEL)           // VF bf16 [bp][512][32][4]
#define QSP0 (VF0 + AEL)            // q split bf16 frag-native [tile][3][8][32][4]
#define SPLEN 393216
#define KSP0 (QSP0 + SPLEN)
#define MB0  (KSP0 + SPLEN)         // pmask u64 x MWORDS, then nmask
#define MWORDS (BB*32*SS)           // 262144 u64 per mask
#define PART0 (MB0 + 4*MWORDS)
#define PSLOT (36*8192)
#define TINY 1e-30f

typedef __attribute__((ext_vector_type(16))) float f32x16;
typedef __attribute__((ext_vector_type(4)))  short bf16x4;
typedef unsigned short ushortt;
typedef unsigned long long u64;

#if defined(__has_builtin)
#if __has_builtin(__builtin_amdgcn_mfma_f32_32x32x8bf16_1k)
#define HAVE_MFMA328 1
#endif
#if __has_builtin(__builtin_amdgcn_perm)
#define HAVE_PERM 1
#endif
#endif

__device__ __forceinline__ f32x16 mfma328(bf16x4 a, bf16x4 b, f32x16 c) {
#ifdef HAVE_MFMA328
    return __builtin_amdgcn_mfma_f32_32x32x8bf16_1k(a, b, c, 0, 0, 0);
#else
    f32x16 d;
    asm volatile("v_mfma_f32_32x32x8_bf16 %0, %1, %2, %3\n\t"
                 "s_nop 7\n\t"
                 "s_nop 7\n\t"
                 "s_nop 3"
                 : "=&v"(d) : "v"(a), "v"(b), "v"(c));
    return d;
#endif
}

__device__ __forceinline__ float fexp2(float x) {
#if defined(__has_builtin)
#if __has_builtin(__builtin_amdgcn_exp2f)
    return __builtin_amdgcn_exp2f(x);
#else
    return exp2f(x);
#endif
#else
    return exp2f(x);
#endif
}

__device__ __forceinline__ ushortt b1(float a) {
    unsigned u = __float_as_uint(a);
    u += 0x7fffu + ((u >> 16) & 1u);
    return (ushortt)(u >> 16);
}
__device__ __forceinline__ float tof(ushortt h) {
    return __uint_as_float(((unsigned)h) << 16);
}
__device__ __forceinline__ unsigned bfpair(float a, float b) {
    unsigned ua = __float_as_uint(a), ub = __float_as_uint(b);
    ua += 0x7fffu + ((ua >> 16) & 1u);
    ub += 0x7fffu + ((ub >> 16) & 1u);
    return (ua >> 16) | (ub & 0xffff0000u);
}
// truncation-pack of two positive f32 -> {bf16(a) lo, bf16(b) hi} in 1 v_perm_b32
__device__ __forceinline__ unsigned bfpairT(float a, float b) {
#ifdef HAVE_PERM
    return __builtin_amdgcn_perm(__float_as_uint(b), __float_as_uint(a),
                                 0x07060302u);
#else
    return (__float_as_uint(a) >> 16) | (__float_as_uint(b) & 0xffff0000u);
#endif
}
__device__ __forceinline__ bf16x4 packT(float p0, float p1, float p2, float p3) {
    union { unsigned u[2]; bf16x4 v; } c;
    c.u[0] = bfpairT(p0, p1);
    c.u[1] = bfpairT(p2, p3);
    return c.v;
}

// ---------- kernel 1: projections, wave-uniform mat; frag-native split stores ----------
__global__ __launch_bounds__(256) void k1_proj(
    const float* __restrict__ feat,
    const float* __restrict__ qw, const float* __restrict__ qb,
    const float* __restrict__ kw, const float* __restrict__ kb,
    const float* __restrict__ paw, const float* __restrict__ pab,
    const float* __restrict__ naw, const float* __restrict__ nab,
    const float* __restrict__ f1w, const float* __restrict__ f2w,
    const float* __restrict__ f3w,
    float* __restrict__ wsf) {
    __shared__ float fls[64 * 33];
    int tid = threadIdx.x;
    int w = tid >> 6, lane = tid & 63;
    int rt = blockIdx.x;
    int mat = blockIdx.y * 4 + w;

    {
        int fl = tid * 8;
        int rl = fl >> 5, dd = fl & 31;
        const float* src = feat + ((size_t)(rt * 64 + rl)) * DMOD + dd;
        float4 a = *(const float4*)(src);
        float4 b4 = *(const float4*)(src + 4);
        float* dst = fls + rl * 33 + dd;
        dst[0] = a.x; dst[1] = a.y; dst[2] = a.z; dst[3] = a.w;
        dst[4] = b4.x; dst[5] = b4.y; dst[6] = b4.z; dst[7] = b4.w;
    }
    __syncthreads();

    const float* W; const float* Bv; float sc = 1.f;
    switch (mat) {
        case 0: W = qw;        Bv = qb;       break;
        case 1: W = kw;        Bv = kb;       break;
        case 2: W = paw;       Bv = pab;      sc = 0.5101370246954918f; break;
        case 3: W = paw+1024;  Bv = pab+32;   break;
        case 4: W = paw+2048;  Bv = pab+64;   break;
        case 5: W = naw;       Bv = nab;      sc = 0.5101370246954918f; break;
        case 6: W = naw+1024;  Bv = nab+32;   break;
        default:W = naw+2048;  Bv = nab+64;   break;
    }

    int row = rt * 64 + lane;
    const float* fr = fls + lane * 33;
    float acc[32];
    #pragma unroll
    for (int o4 = 0; o4 < 32; o4 += 4) {
        float a0 = Bv[o4], a1 = Bv[o4+1], a2 = Bv[o4+2], a3 = Bv[o4+3];
        #pragma unroll
        for (int d = 0; d < DMOD; d++) {
            float fv = fr[d];
            a0 += fv * W[(o4+0)*DMOD + d];
            a1 += fv * W[(o4+1)*DMOD + d];
            a2 += fv * W[(o4+2)*DMOD + d];
            a3 += fv * W[(o4+3)*DMOD + d];
        }
        acc[o4] = a0; acc[o4+1] = a1; acc[o4+2] = a2; acc[o4+3] = a3;
    }

    if (mat < 2) {
        if (mat == 0) {
            float cc[4];
            #pragma unroll
            for (int h = 0; h < 4; h++) {
                float s = 0.f;
                #pragma unroll
                for (int a = 0; a < 4; a++) {
                    float t = 0.f;
                    #pragma unroll
                    for (int bb = 0; bb < 8; bb++) t += f2w[a*8+bb] * f1w[bb*4+h];
                    s += f3w[a] * t;
                }
                cc[h] = s * 0.35355339059327373f;
            }
            #pragma unroll
            for (int o = 0; o < 32; o++) acc[o] *= cc[o >> 3];
        }
        // 3-term split, stored frag-native:
        // offset = ((tile*3 + t)*8 + (ks*2+hi))*128 + li*4 + e
        ushortt* base = (ushortt*)(wsf + (mat == 0 ? QSP0 : KSP0));
        size_t tb = (size_t)(row >> 5) * 3;
        int li2 = row & 31;
        ushortt sp[3][32];
        #pragma unroll
        for (int o = 0; o < 32; o++) {
            float v = acc[o];
            ushortt h0 = b1(v);
            float r1 = v - tof(h0);
            ushortt m0 = b1(r1);
            float r2 = r1 - tof(m0);
            sp[0][o] = h0; sp[1][o] = m0; sp[2][o] = b1(r2);
        }
        #pragma unroll
        for (int t = 0; t < 3; t++) {
            ushortt* tb2 = base + (tb + t) * 1024 + li2 * 4;
            #pragma unroll
            for (int ks = 0; ks < 4; ks++) {
                #pragma unroll
                for (int hi2 = 0; hi2 < 2; hi2++) {
                    int c0 = ks*8 + hi2*4;
                    *(ushort4*)(tb2 + (ks*2 + hi2) * 128) =
                        make_ushort4(sp[t][c0], sp[t][c0+1], sp[t][c0+2], sp[t][c0+3]);
                }
            }
        }
        return;
    }

    #pragma unroll
    for (int o = 0; o < 32; o++) acc[o] *= sc;
    int b = row >> 11, r2i = row & 2047;
    int pn = (mat >= 5);
    int bp = (b << 1) | pn;
    int m3 = mat - (pn ? 5 : 2);
    if (m3 < 2) {
        unsigned pk[16];
        #pragma unroll
        for (int i = 0; i < 16; i++) pk[i] = bfpair(acc[2*i], acc[2*i+1]);
        unsigned* dst = (unsigned*)((ushortt*)(wsf + (m3 == 0 ? QBF0 : KBF0))
                         + (size_t)bp*65536 + (size_t)r2i*32);
        #pragma unroll
        for (int i = 0; i < 4; i++)
            *(uint4*)(dst + 4*i) = make_uint4(pk[4*i], pk[4*i+1], pk[4*i+2], pk[4*i+3]);
    } else {
        ushortt* vf = (ushortt*)(wsf + VF0)
                         + (size_t)bp*65536 + (size_t)(r2i>>2)*128 + (r2i&3);
        #pragma unroll
        for (int o = 0; o < 32; o++)
            vf[(size_t)o*4] = b1(acc[o]);
    }
}

// ---------- kernel A: MFMA fused-score sign + dmask fold -> packed p/n masks ----------
// grid (jq=8, is=64, b=4) = 2048 blocks; wave w: one 64-j window.
// Q/K split fragments are frag-native -> coalesced 8B loads.
__global__ __launch_bounds__(256) void kA_mask(
    const float* __restrict__ dmask,
    const ushortt* __restrict__ qsp, const ushortt* __restrict__ ksp,
    u64* __restrict__ pmout,
    const float* __restrict__ f1b, const float* __restrict__ f2w,
    const float* __restrict__ f2b, const float* __restrict__ f3w,
    const float* __restrict__ f3b) {
    int tid = threadIdx.x;
    int w = tid >> 6, l = tid & 63, li = l & 31, hi = l >> 5;
    int b = blockIdx.z;
    int it = blockIdx.y * 32;
    int j0 = blockIdx.x * 256 + w * 64;

    float cbv = f3b[0];
    #pragma unroll
    for (int a = 0; a < 4; a++) {
        float t = f2b[a];
        #pragma unroll
        for (int bb = 0; bb < 8; bb++) t += f2w[a*8+bb] * f1b[bb];
        cbv += f3w[a] * t;
    }

    // Q fragments: tile (b*SS+it)>>5
    size_t qtb = (size_t)((b*SS + it) >> 5) * 3;
    bf16x4 qa[3][4];
    #pragma unroll
    for (int t = 0; t < 3; t++) {
        const ushortt* qb2 = qsp + (qtb + t) * 1024 + hi * 128 + li * 4;
        #pragma unroll
        for (int ks = 0; ks < 4; ks++)
            qa[t][ks] = *(const bf16x4*)(qb2 + ks * 256);
    }

    const float* dmbase = dmask + (size_t)b*SS*SS;
    u64* pm = pmout + (size_t)b*32*SS;
    u64* nm = pmout + MWORDS + (size_t)b*32*SS;

    f32x16 cin;
    #pragma unroll
    for (int r = 0; r < 16; r++) cin[r] = cbv;

    int j64 = j0 >> 6;
    // prefetch dm floats for this 64-j window (issued before MFMA chain)
    float dm0[16], dm1[16];
    #pragma unroll
    for (int r = 0; r < 16; r++) {
        int i = it + (r & 3) + 8*(r >> 2) + 4*hi;
        const float* dr = dmbase + (size_t)i*SS + j0 + li;
        dm0[r] = dr[0];
        dm1[r] = dr[32];
    }
    f32x16 St[2];
    #pragma unroll
    for (int t2 = 0; t2 < 2; t2++) {
        int jt = j0 + t2*32;
        size_t ktb = (size_t)((b*SS + jt) >> 5) * 3;
        bf16x4 kb[3][4];
        #pragma unroll
        for (int t = 0; t < 3; t++) {
            const ushortt* kb2 = ksp + (ktb + t) * 1024 + hi * 128 + li * 4;
            #pragma unroll
            for (int ks = 0; ks < 4; ks++)
                kb[t][ks] = *(const bf16x4*)(kb2 + ks * 256);
        }
        f32x16 S = cin;
        #pragma unroll
        for (int ks = 0; ks < 4; ks++) S = mfma328(qa[0][ks], kb[0][ks], S);
        #pragma unroll
        for (int ks = 0; ks < 4; ks++) S = mfma328(qa[0][ks], kb[1][ks], S);
        #pragma unroll
        for (int ks = 0; ks < 4; ks++) S = mfma328(qa[1][ks], kb[0][ks], S);
        #pragma unroll
        for (int ks = 0; ks < 4; ks++) S = mfma328(qa[0][ks], kb[2][ks], S);
        #pragma unroll
        for (int ks = 0; ks < 4; ks++) S = mfma328(qa[2][ks], kb[0][ks], S);
        #pragma unroll
        for (int ks = 0; ks < 4; ks++) S = mfma328(qa[1][ks], kb[1][ks], S);
        St[t2] = S;
    }
    #pragma unroll
    for (int r = 0; r < 16; r++) {
        bool a0 = (dm0[r] != 0.f), a1 = (dm1[r] != 0.f);
        bool s0 = St[0][r] > 0.f, s1 = St[1][r] > 0.f;
        u64 b0p = __ballot(s0 && a0);
        u64 b1p = __ballot(s1 && a1);
        u64 b0n = __ballot(!s0 && a0);
        u64 b1n = __ballot(!s1 && a1);
        u64 pA = (b0p & 0xffffffffull) | (b1p << 32);
        u64 pB = (b0p >> 32) | (b1p & 0xffffffff00000000ull);
        u64 nA = (b0n & 0xffffffffull) | (b1n << 32);
        u64 nB = (b0n >> 32) | (b1n & 0xffffffff00000000ull);
        int iA = it + (r & 3) + 8*(r >> 2);
        if (l == 0) {
            pm[(size_t)j64*SS + iA] = pA;
            nm[(size_t)j64*SS + iA] = nA;
        }
        if (l == 32) {
            pm[(size_t)j64*SS + iA + 4] = pB;
            nm[(size_t)j64*SS + iA + 4] = nB;
        }
    }
}

// ---------- kernel B: MFMA masked attention — head-split (r22, no setprio) ----------
// grid (nch, 16, 16): z = (b<<2)|(pn<<1)|hp; block 256 = 4 waves, wave = 32-row tile
__global__ __launch_bounds__(256) void kB_attn(
    const ushortt* __restrict__ qbf,
    const ushortt* __restrict__ kbf,
    const ushortt* __restrict__ vff,
    const u64* __restrict__ mall,
    float* __restrict__ part, int CJ, int NCH) {
    int tid = threadIdx.x;
    int w = tid >> 6, l = tid & 63, li = l & 31, hi = l >> 5;
    int jc = blockIdx.x, rg = blockIdx.y, z = blockIdx.z;
    int b = z >> 2, pn = (z >> 1) & 1, hp = z & 1;
    int bp = (b << 1) | pn;
    int h0 = hp * 2;
    int it32 = rg * 128 + w * 32;

    const ushortt* qrow = qbf + (size_t)bp*65536 + (size_t)(it32 + li)*32 + 4*hi;
    bf16x4 qf[2];
    #pragma unroll
    for (int hh = 0; hh < 2; hh++) qf[hh] = *(const bf16x4*)(qrow + (h0+hh)*8);

    const ushortt* kbase = kbf + (size_t)bp*65536 + (size_t)li*32 + 4*hi;
    const ushortt* vbase = vff + (size_t)bp*65536 + (size_t)hi*128;
    const u64* msk = mall + (size_t)pn*MWORDS + (size_t)b*32*SS + (it32 + li);

    bool isl8 = (li == 8);
    bf16x4 ones4;
    {
        union { ushortt s[4]; bf16x4 v; } o;
        o.s[0] = o.s[1] = o.s[2] = o.s[3] = 0x3F80;   // bf16 1.0
        ones4 = o.v;
    }

    f32x16 zero16;
    #pragma unroll
    for (int r = 0; r < 16; r++) zero16[r] = 0.f;
    f32x16 oacc[2];
    #pragma unroll
    for (int hh = 0; hh < 2; hh++)
        #pragma unroll
        for (int r = 0; r < 16; r++) oacc[hh][r] = 0.f;

    int j0 = jc * CJ;
    for (int jw = 0; jw < CJ; jw += 64) {
        u64 mw = msk[(size_t)((j0 + jw) >> 6) * SS];
        #pragma unroll
        for (int half = 0; half < 2; half++) {
            int jt = j0 + jw + half*32;
            unsigned m32 = (unsigned)(mw >> (half*32));
            const ushortt* krow = kbase + (size_t)jt*32;
            const ushortt* vrow = vbase + (size_t)(jt>>2)*128;
            #pragma unroll
            for (int hh = 0; hh < 2; hh++) {
                int h = h0 + hh;
                bf16x4 kf = *(const bf16x4*)(krow + h*8);
                int vcol = ((h*8 + li) & 31) * 4;
                bf16x4 vf0 = *(const bf16x4*)(vrow + 0*256 + vcol);
                bf16x4 vf1 = *(const bf16x4*)(vrow + 1*256 + vcol);
                bf16x4 vf2 = *(const bf16x4*)(vrow + 2*256 + vcol);
                bf16x4 vf3 = *(const bf16x4*)(vrow + 3*256 + vcol);
                if (isl8) { vf0 = ones4; vf1 = ones4; vf2 = ones4; vf3 = ones4; }
                f32x16 sacc = mfma328(kf, qf[hh], zero16);
                float p[16];
                #pragma unroll
                for (int r = 0; r < 16; r++) {
                    int sh = (r & 3) + 8*(r >> 2) + 4*hi;
                    float e = fexp2(sacc[r]);
                    p[r] = ((m32 >> sh) & 1u) ? e : TINY;
                }
                oacc[hh] = mfma328(packT(p[0],  p[1],  p[2],  p[3]),  vf0, oacc[hh]);
                oacc[hh] = mfma328(packT(p[4],  p[5],  p[6],  p[7]),  vf1, oacc[hh]);
                oacc[hh] = mfma328(packT(p[8],  p[9],  p[10], p[11]), vf2, oacc[hh]);
                oacc[hh] = mfma328(packT(p[12], p[13], p[14], p[15]), vf3, oacc[hh]);
            }
        }
    }
    // epilogue: partial slot [pn*NCH+jc][36][8192]; k: 0..3 l[h] (ones column),
    // 4..35 a[h*8+d]
    float* base2 = part + (size_t)(pn * NCH + jc) * PSLOT + (size_t)b * SS;
    if (isl8) {
        #pragma unroll
        for (int hh = 0; hh < 2; hh++) {
            int h = h0 + hh;
            #pragma unroll
            for (int r = 0; r < 16; r++) {
                int irow = it32 + (r & 3) + 8*(r >> 2) + 4*hi;
                base2[(size_t)h * 8192 + irow] = oacc[hh][r];
            }
        }
    }
    if (li < 8) {
        #pragma unroll
        for (int hh = 0; hh < 2; hh++) {
            int h = h0 + hh;
            #pragma unroll
            for (int r = 0; r < 16; r++) {
                int irow = it32 + (r & 3) + 8*(r >> 2) + 4*hi;
                base2[(size_t)(4 + h*8 + li) * 8192 + irow] = oacc[hh][r];
            }
        }
    }
}

// ---------- kernel 3a: reduce split-K partials (unchanged) ----------
__global__ __launch_bounds__(256) void k3a_red(float* __restrict__ part, int NCH) {
    int idx = blockIdx.x * 256 + threadIdx.x;
    size_t e = (size_t)idx * 4;
    int pn = (int)(e / PSLOT);
    size_t off = e - (size_t)pn * PSLOT;
    float* base = part + (size_t)pn * NCH * PSLOT + off;
    float4 s = *(const float4*)base;
    for (int c = 1; c < NCH; c++) {
        float4 v = *(const float4*)(base + (size_t)c * PSLOT);
        s.x += v.x; s.y += v.y; s.z += v.z; s.w += v.w;
    }
    *(float4*)base = s;
}

// ---------- kernel 3b: normalize + out-proj + gate (unchanged) ----------
__global__ __launch_bounds__(256) void k3b_fin(
    const float* __restrict__ part, int NCH,
    const float* __restrict__ paw, const float* __restrict__ pab,
    const float* __restrict__ naw, const float* __restrict__ nab,
    const float* __restrict__ vpw, const float* __restrict__ vpb,
    const float* __restrict__ vnw, const float* __restrict__ vnb,
    const float* __restrict__ gpw, const float* __restrict__ gpb,
    float* __restrict__ out) {
    __shared__ float sums[8][72];
    __shared__ float Pl[8][64];
    __shared__ float pnv[8][64];
    int tid = threadIdx.x;
    int r = tid >> 5, o = tid & 31;
    int row = blockIdx.x * 8 + r;
    const float* b0 = part + row;
    const float* b1 = part + (size_t)NCH * PSLOT + row;
    for (int v = o; v < 72; v += 32) {
        int pn = v >= 36;
        int k = v - 36 * pn;
        sums[r][v] = (pn ? b1 : b0)[(size_t)k * 8192];
    }
    __syncthreads();
    Pl[r][o]      = sums[r][4 + o]  / sums[r][o >> 3];
    Pl[r][32 + o] = sums[r][40 + o] / sums[r][36 + (o >> 3)];
    __syncthreads();
    const float* pw3 = paw + 3*1024; const float* pb3 = pab + 3*32;
    const float* nw3 = naw + 3*1024; const float* nb3 = nab + 3*32;
    float pv = pb3[o], nv = nb3[o];
    #pragma unroll
    for (int d = 0; d < 32; d++) {
        pv += Pl[r][d]      * pw3[o*32 + d];
        nv += Pl[r][32 + d] * nw3[o*32 + d];
    }
    pnv[r][o] = pv; pnv[r][32 + o] = nv;
    __syncthreads();
    float vp = vpb[o], vn = vnb[o], ep = gpb[o], en = gpb[o];
    #pragma unroll
    for (int d = 0; d < 32; d++) {
        float pd = pnv[r][d], nd = pnv[r][32 + d];
        vp += pd * vpw[o*32 + d];
        vn += nd * vnw[o*32 + d];
        ep += pd * gpw[o*32 + d];
        en += nd * gpw[o*32 + d];
    }
    float g = 1.0f / (1.0f + __expf(en - ep));
    out[(size_t)row * 32 + o] = vp * g + vn * (1.0f - g);
}

extern "C" void kernel_launch(void* const* d_in, const int* in_sizes, int n_in,
                              void* d_out, int out_size, void* d_ws, size_t ws_size,
                              hipStream_t stream) {
    const float* feat  = (const float*)d_in[0];
    const float* dmask = (const float*)d_in[1];
    const float* qw  = (const float*)d_in[2];  const float* qb  = (const float*)d_in[3];
    const float* kw  = (const float*)d_in[4];  const float* kb  = (const float*)d_in[5];
    const float* f1w = (const float*)d_in[6];  const float* f1b = (const float*)d_in[7];
    const float* f2w = (const float*)d_in[8];  const float* f2b = (const float*)d_in[9];
    const float* f3w = (const float*)d_in[10]; const float* f3b = (const float*)d_in[11];
    const float* paw = (const float*)d_in[12]; const float* pab = (const float*)d_in[13];
    const float* naw = (const float*)d_in[14]; const float* nab = (const float*)d_in[15];
    const float* vpw = (const float*)d_in[16]; const float* vpb = (const float*)d_in[17];
    const float* vnw = (const float*)d_in[18]; const float* vnb = (const float*)d_in[19];
    const float* gpw = (const float*)d_in[20]; const float* gpb = (const float*)d_in[21];
    float* wsf = (float*)d_ws;
    float* out = (float*)d_out;

    size_t avail = ws_size / 4;
    int nch = 1;
    if (avail > (size_t)PART0) {
        size_t per = (size_t)2 * PSLOT;
        size_t m = (avail - PART0) / per;
        nch = (m >= 8) ? 8 : (m >= 4) ? 4 : (m >= 2) ? 2 : 1;
    }
    int cj = SS / nch;
    float* part = wsf + PART0;

    const ushortt* qbfu = (const ushortt*)(wsf + QBF0);
    const ushortt* kbfu = (const ushortt*)(wsf + KBF0);
    const ushortt* vffu = (const ushortt*)(wsf + VF0);
    const ushortt* qspu = (const ushortt*)(wsf + QSP0);
    const ushortt* kspu = (const ushortt*)(wsf + KSP0);

    hipLaunchKernelGGL(k1_proj, dim3(128, 2), dim3(256), 0, stream,
                       feat, qw, qb, kw, kb, paw, pab, naw, nab,
                       f1w, f2w, f3w, wsf);
    hipLaunchKernelGGL(kA_mask, dim3(8, 64, BB), dim3(256), 0, stream,
                       dmask, qspu, kspu, (u64*)(wsf + MB0),
                       f1b, f2w, f2b, f3w, f3b);
    hipLaunchKernelGGL(kB_attn, dim3(nch, 16, BB*4), dim3(256), 0, stream,
                       qbfu, kbfu, vffu,
                       (const u64*)(wsf + MB0), part, cj, nch);
    if (nch > 1)
        hipLaunchKernelGGL(k3a_red, dim3(576), dim3(256), 0, stream, part, nch);
    hipLaunchKernelGGL(k3b_fin, dim3(1024), dim3(256), 0, stream,
                       part, nch, paw, pab, naw, nab, vpw, vpb, vnw, vnb, gpw, gpb,
                       out);
}